// Round 8
// baseline (335.492 us; speedup 1.0000x reference)
//
#include <hip/hip_runtime.h>

// GraphAE: 2x GCNConv encoder + 2-layer MLP decoder.
// N=50000, IN=128, HID=256, LAT=64, E=800000. fp32 in/out.
//
// R18 changes vs R17:
//  - 16KB LDS kernels: stage-A->B intermediate (o1/dsm) stored as single
//    f16 plane (16KB) instead of bf16 hi/lo (32KB); converted f16->hi/lo
//    bf16 in registers at stage-B read (f16 2^-11 intermediate adds ~4e-5
//    to zs, negligible vs absmax 2.44e-4). xa/zt tiles alias inside.
//    R17 counters: enc 74us @ 31% occupancy, 1.2 TB/s gather vs 2.9-3.7
//    demonstrated -> latency-bound on resident waves. Grid = 1563 blocks =
//    24.4 waves/CU max; 16KB removes the LDS cap so the WHOLE grid resides.
//  - enc gather 8-deep (full~=8 per 64-edge chunk); dec stays 4-deep
//    (full~=4). R13's 8-deep null was in the BW-bound f32 regime.
//  - R17: LDS time-multiplex (+20us). R16: agg-into-GEMM fusion (FETCH
//    189->81MB). R14: f16 gather planes. R11: hist/fill dst-partition.
// (R15 grid-barrier fusion REVERTED: spin acquire = L2-inv storm on gfx950.)

#define IN_CH  128
#define HIDDEN 256
#define LATENT 64

typedef unsigned short u16;
typedef unsigned int u32;
typedef __bf16 bf16x8 __attribute__((ext_vector_type(8)));
typedef float f32x4 __attribute__((ext_vector_type(4)));
typedef _Float16 f16x4 __attribute__((ext_vector_type(4)));
typedef _Float16 f16x8 __attribute__((ext_vector_type(8)));
typedef u16 u16x8 __attribute__((ext_vector_type(8)));

static __device__ __forceinline__ float4 ld4(const float* p) {
    return *reinterpret_cast<const float4*>(p);
}
static __device__ __forceinline__ void acc4(float4& a, float4 v) {
    a.x += v.x; a.y += v.y; a.z += v.z; a.w += v.w;
}
static __device__ __forceinline__ f16x4 ldh4(const _Float16* p) {
    return *reinterpret_cast<const f16x4*>(p);
}
static __device__ __forceinline__ void acch(float4& a, f16x4 v) {
    a.x += (float)v[0]; a.y += (float)v[1]; a.z += (float)v[2]; a.w += (float)v[3];
}

// truncating hi/lo split: hi = top16(v); lo = top16(v - hi). v-hi exact.
static __device__ __forceinline__ void split_bf16(float v, u16& hi, u16& lo) {
    u32 b = __float_as_uint(v);
    hi = (u16)(b >> 16);
    float hf = __uint_as_float(b & 0xFFFF0000u);
    lo = (u16)(__float_as_uint(v - hf) >> 16);
}

// f16x8 -> hi/lo bf16x8 (register-side split for stage-B A-operand)
static __device__ __forceinline__ void cvt_hilo(f16x8 a, bf16x8& h, bf16x8& l) {
    u16x8 hh, ll;
#pragma unroll
    for (int k = 0; k < 8; k++) {
        float v = (float)a[k];
        u16 hi, lo;
        split_bf16(v, hi, lo);
        hh[k] = hi;
        ll[k] = lo;
    }
    h = __builtin_bit_cast(bf16x8, hh);
    l = __builtin_bit_cast(bf16x8, ll);
}

// tiled-layout offset (elements). K multiple of 8; row tiles of 16.
static __device__ __forceinline__ long tix(int row, int k, int K) {
    return ((long)(row >> 4) * (K >> 3) + (k >> 3)) * 128 + ((row & 15) << 3) + (k & 7);
}

#define MFMA3(ACC, AH, AL, BH, BL)                                             \
    ACC = __builtin_amdgcn_mfma_f32_16x16x32_bf16(AH, BH, ACC, 0, 0, 0);       \
    ACC = __builtin_amdgcn_mfma_f32_16x16x32_bf16(AH, BL, ACC, 0, 0, 0);       \
    ACC = __builtin_amdgcn_mfma_f32_16x16x32_bf16(AL, BH, ACC, 0, 0, 0);

// ---------------- graph structure kernels ----------------

// Partitioned histogram: block b handles edge chunk (b>>3), dst range (b&7).
__global__ void hist_kernel(const int* __restrict__ ei, int E,
                            int* __restrict__ counts, int nper) {
    int part = blockIdx.x & 7;
    int e = (blockIdx.x >> 3) * 256 + threadIdx.x;
    if (e >= E) return;
    int d = ei[E + e];
    if ((unsigned)(d - part * nper) < (unsigned)nper) atomicAdd(&counts[d], 1);
}

// scan1 (blocks < nblk) with dinv emit; wsplit rides along (blocks >= nblk).
__global__ void scan1_wsplit_kernel(
    const int* __restrict__ counts, int* __restrict__ rowptr,
    int* __restrict__ blocksums, float* __restrict__ dinv, int N, int nblk,
    const float* __restrict__ W1, const float* __restrict__ W2,
    const float* __restrict__ Wd1, const float* __restrict__ Wd2,
    u16* __restrict__ w1h, u16* __restrict__ w1l, u16* __restrict__ w2h, u16* __restrict__ w2l,
    u16* __restrict__ wd1h, u16* __restrict__ wd1l, u16* __restrict__ wd2h, u16* __restrict__ wd2l) {
    __shared__ int sh[256];
    int tid = threadIdx.x;
    if ((int)blockIdx.x < nblk) {
        int i = blockIdx.x * 256 + tid;
        int v = (i < N) ? counts[i] : 0;
        if (i < N) dinv[i] = rsqrtf((float)v + 1.0f);
        sh[tid] = v;
        __syncthreads();
        for (int off = 1; off < 256; off <<= 1) {
            int t = (tid >= off) ? sh[tid - off] : 0;
            __syncthreads();
            sh[tid] += t;
            __syncthreads();
        }
        if (i < N) rowptr[i] = sh[tid] - v;
        if (tid == 255) blocksums[blockIdx.x] = sh[255];
    } else {
        int idx = ((int)blockIdx.x - nblk) * 256 + tid;
        if (idx < 98304) {
            const float* W; u16 *H, *L; int K, Nn, base;
            if (idx < 32768)      { W = W1;  H = w1h;  L = w1l;  K = 128; Nn = 256; base = idx; }
            else if (idx < 49152) { W = W2;  H = w2h;  L = w2l;  K = 256; Nn = 64;  base = idx - 32768; }
            else if (idx < 65536) { W = Wd1; H = wd1h; L = wd1l; K = 64;  Nn = 256; base = idx - 49152; }
            else                  { W = Wd2; H = wd2h; L = wd2l; K = 256; Nn = 128; base = idx - 65536; }
            int k = base / Nn, n = base % Nn;
            u16 h, l;
            split_bf16(W[base], h, l);
            long o = tix(n, k, K);
            H[o] = h;
            L[o] = l;
        }
    }
}

// scan3 (+inlined scan2: blockoffs[b] = sum blocksums[0..b)) + prescale.
__global__ void scan3_prescale_kernel(
    int* __restrict__ rowptr, const int* __restrict__ blocksums, int* __restrict__ next,
    const float* __restrict__ x, const float* __restrict__ dinv, _Float16* __restrict__ xsh,
    int N, int total4, int nblk) {
    __shared__ int sh[256];
    const int b = blockIdx.x;
    const int tid = threadIdx.x;
    int boff = 0;
    if (b < nblk) {
        int s = 0;
        for (int j = tid; j < b; j += 256) s += blocksums[j];
        sh[tid] = s;
        __syncthreads();
        for (int off = 128; off > 0; off >>= 1) {
            if (tid < off) sh[tid] += sh[tid + off];
            __syncthreads();
        }
        boff = sh[0];
        if (b == nblk - 1 && tid == 0) rowptr[N] = boff + blocksums[b];
    }
    int i = b * 256 + tid;
    if (b < nblk && i < N) {
        int r = rowptr[i] + boff;
        rowptr[i] = r;
        next[i] = r;
    }
    if (i < total4) {
        float s = dinv[i >> 5];
        float4 v = ld4(&x[(long)i * 4]);
        f16x4 h;
        h[0] = (_Float16)(v.x * s);
        h[1] = (_Float16)(v.y * s);
        h[2] = (_Float16)(v.z * s);
        h[3] = (_Float16)(v.w * s);
        *reinterpret_cast<f16x4*>(&xsh[(long)i * 4]) = h;
    }
}

// Partitioned CSR fill: block b handles edge chunk (b>>3), dst range (b&7).
__global__ void fill_kernel(const int* __restrict__ ei, int E,
                            int* __restrict__ next, int* __restrict__ col, int nper) {
    int part = blockIdx.x & 7;
    int e = (blockIdx.x >> 3) * 256 + threadIdx.x;
    if (e >= E) return;
    int d = ei[E + e];
    if ((unsigned)(d - part * nper) < (unsigned)nper) {
        int s = ei[e];
        int pos = atomicAdd(&next[d], 1);
        col[pos] = s;
    }
}

// ---------------- fused agg+encoder (16KB LDS) ----------------
// Prologue: each wave aggregates 8 nodes (f16 gather 8-deep, fp32 acc, dinv
// scale) -> LDS bf16 hi/lo xa tile [32x128] (16KB). Stage A reads xa frags.
// o1 (stage A->B) is stored f16 [32x256] ALIASED over the same 16KB; stage B
// converts f16 -> hi/lo bf16 in registers.
__global__ __launch_bounds__(256, 6) void enc_fused(
    const _Float16* __restrict__ xsh, const int* __restrict__ rowptr,
    const int* __restrict__ col, const float* __restrict__ dinv,
    const u16* __restrict__ w1h, const u16* __restrict__ w1l,
    const u16* __restrict__ w2h, const u16* __restrict__ w2l,
    const float* __restrict__ b1, _Float16* __restrict__ zsh, int M) {
    __shared__ u16 smem[2][32 * 128];  // 16 KB: xa hi/lo planes -> o1 f16

    const int tid = threadIdx.x;
    const int wid = tid >> 6, lane = tid & 63, quad = lane >> 4, lm = lane & 15;
    const int rt0 = blockIdx.x * 2;
    const int last_rt = (M >> 4) - 1;
    u16* const xa0 = &smem[0][0];
    u16* const xa1 = &smem[1][0];
    _Float16* const o1f = (_Float16*)&smem[0][0];  // [32*256] f16, aliased

    // ---- agg prologue (aggx): 8 nodes per wave, 8-deep pipeline ----
    {
        const int slot = lane >> 5;
        const int c = (lane & 31) * 4;
        for (int r8 = 0; r8 < 8; r8++) {
            int node = blockIdx.x * 32 + wid * 8 + r8;
            if (node >= M) break;
            float4 a0 = make_float4(0.f, 0.f, 0.f, 0.f);
            float4 a1 = a0, a2 = a0, a3 = a0, a4 = a0, a5 = a0, a6 = a0, a7 = a0;
            if (slot == 0) acch(a0, ldh4(&xsh[(long)node * 128 + c]));
            int beg = rowptr[node];
            int end = rowptr[node + 1];
            for (int cb = beg; cb < end; cb += 64) {
                int cnt = min(64, end - cb);
                int cv = (lane < cnt) ? col[cb + lane] : 0;
                int full = cnt >> 1;
                int trips = (cnt + 1) >> 1;
                int t = 0;
                for (; t + 8 <= full; t += 8) {
                    int j = slot + 2 * t;
                    int s0 = __shfl(cv, j);
                    int s1 = __shfl(cv, j + 2);
                    int s2 = __shfl(cv, j + 4);
                    int s3 = __shfl(cv, j + 6);
                    int s4 = __shfl(cv, j + 8);
                    int s5 = __shfl(cv, j + 10);
                    int s6 = __shfl(cv, j + 12);
                    int s7 = __shfl(cv, j + 14);
                    f16x4 v0 = ldh4(&xsh[(long)s0 * 128 + c]);
                    f16x4 v1 = ldh4(&xsh[(long)s1 * 128 + c]);
                    f16x4 v2 = ldh4(&xsh[(long)s2 * 128 + c]);
                    f16x4 v3 = ldh4(&xsh[(long)s3 * 128 + c]);
                    f16x4 v4 = ldh4(&xsh[(long)s4 * 128 + c]);
                    f16x4 v5 = ldh4(&xsh[(long)s5 * 128 + c]);
                    f16x4 v6 = ldh4(&xsh[(long)s6 * 128 + c]);
                    f16x4 v7 = ldh4(&xsh[(long)s7 * 128 + c]);
                    acch(a0, v0); acch(a1, v1); acch(a2, v2); acch(a3, v3);
                    acch(a4, v4); acch(a5, v5); acch(a6, v6); acch(a7, v7);
                }
                for (; t + 4 <= full; t += 4) {
                    int j = slot + 2 * t;
                    int s0 = __shfl(cv, j);
                    int s1 = __shfl(cv, j + 2);
                    int s2 = __shfl(cv, j + 4);
                    int s3 = __shfl(cv, j + 6);
                    f16x4 v0 = ldh4(&xsh[(long)s0 * 128 + c]);
                    f16x4 v1 = ldh4(&xsh[(long)s1 * 128 + c]);
                    f16x4 v2 = ldh4(&xsh[(long)s2 * 128 + c]);
                    f16x4 v3 = ldh4(&xsh[(long)s3 * 128 + c]);
                    acch(a0, v0); acch(a1, v1); acch(a2, v2); acch(a3, v3);
                }
                for (; t < trips; t++) {
                    int j = slot + 2 * t;
                    bool p = j < cnt;
                    int s = __shfl(cv, p ? j : 0);
                    if (p) acch(a0, ldh4(&xsh[(long)s * 128 + c]));
                }
            }
            acc4(a0, a1); acc4(a2, a3); acc4(a4, a5); acc4(a6, a7);
            acc4(a0, a2); acc4(a4, a6); acc4(a0, a4);
            a0.x += __shfl_xor(a0.x, 32);
            a0.y += __shfl_xor(a0.y, 32);
            a0.z += __shfl_xor(a0.z, 32);
            a0.w += __shfl_xor(a0.w, 32);
            if (slot == 0) {
                float di = dinv[node];
                a0.x *= di; a0.y *= di; a0.z *= di; a0.w *= di;
                ushort4 h, l;
                split_bf16(a0.x, h.x, l.x);
                split_bf16(a0.y, h.y, l.y);
                split_bf16(a0.z, h.z, l.z);
                split_bf16(a0.w, h.w, l.w);
                int row = wid * 8 + r8;
                int o = ((row >> 4) * 16 + (c >> 3)) * 128 + ((row & 15) << 3) + (c & 7);
                *(ushort4*)&xa0[o] = h;
                *(ushort4*)&xa1[o] = l;
            }
        }
    }
    __syncthreads();

    // ---- stage A: out1 = relu(xa @ W1 + b1), K=128 (KB=16, KC=4) ----
    f32x4 acc[2][4];
#pragma unroll
    for (int i = 0; i < 2; i++)
#pragma unroll
        for (int j = 0; j < 4; j++) acc[i][j] = (f32x4){0.f, 0.f, 0.f, 0.f};

#pragma unroll
    for (int kc = 0; kc < 4; kc++) {
        const int kb = kc * 4 + quad;
        bf16x8 ah[2], al[2], bh[4], bl[4];
#pragma unroll
        for (int i = 0; i < 2; i++) {
            int lt = (rt0 + i <= last_rt) ? i : (last_rt - rt0);
            int o = (lt * 16 + kb) * 128 + lm * 8;
            ah[i] = *(const bf16x8*)&xa0[o];
            al[i] = *(const bf16x8*)&xa1[o];
        }
#pragma unroll
        for (int j = 0; j < 4; j++) {
            long o = ((long)(wid * 4 + j) * 16 + kb) * 128 + lm * 8;
            bh[j] = *(const bf16x8*)&w1h[o];
            bl[j] = *(const bf16x8*)&w1l[o];
        }
#pragma unroll
        for (int i = 0; i < 2; i++)
#pragma unroll
            for (int j = 0; j < 4; j++) { MFMA3(acc[i][j], ah[i], al[i], bh[j], bl[j]); }
    }
    __syncthreads();  // xa dead only after ALL waves read it (o1f aliases)

    // epilogue A -> LDS f16 tiled (overwrites xa region)
#pragma unroll
    for (int i = 0; i < 2; i++)
#pragma unroll
        for (int j = 0; j < 4; j++) {
            int coln = wid * 64 + j * 16 + lm;
            float bi = b1[coln];
#pragma unroll
            for (int r = 0; r < 4; r++) {
                int row = i * 16 + quad * 4 + r;
                float v = fmaxf(acc[i][j][r] + bi, 0.f);
                int o = ((row >> 4) * 32 + (coln >> 3)) * 128 + ((row & 15) << 3) + (coln & 7);
                o1f[o] = (_Float16)v;
            }
        }
    __syncthreads();

    // ---- stage B: zs = (out1 @ W2) * dinv, K=256 (KB=32, KC=8) ----
    f32x4 acc2[2];
    acc2[0] = (f32x4){0.f, 0.f, 0.f, 0.f};
    acc2[1] = (f32x4){0.f, 0.f, 0.f, 0.f};
#pragma unroll
    for (int kc = 0; kc < 8; kc++) {
        const int kb = kc * 4 + quad;
        bf16x8 ah[2], al[2], bh, bl;
#pragma unroll
        for (int i = 0; i < 2; i++) {
            int o = (i * 32 + kb) * 128 + lm * 8;
            cvt_hilo(*(const f16x8*)&o1f[o], ah[i], al[i]);
        }
        {
            long o = ((long)wid * 32 + kb) * 128 + lm * 8;
            bh = *(const bf16x8*)&w2h[o];
            bl = *(const bf16x8*)&w2l[o];
        }
#pragma unroll
        for (int i = 0; i < 2; i++) { MFMA3(acc2[i], ah[i], al[i], bh, bl); }
    }
#pragma unroll
    for (int i = 0; i < 2; i++) {
        int coln = wid * 16 + lm;
#pragma unroll
        for (int r = 0; r < 4; r++) {
            int row = rt0 * 16 + i * 16 + quad * 4 + r;
            if (row < M) zsh[(long)row * 64 + coln] = (_Float16)(acc2[i][r] * dinv[row]);
        }
    }
}

// ---------------- fused agg+decoder (16KB LDS) ----------------
// Prologue: each wave aggregates 8 nodes of z = dinv*(zs+sum zs)+b2 -> LDS
// bf16 hi/lo z tile [32x64] (8KB) aliased in dsm f16 [32x256] (16KB).
// Stage B converts f16 -> hi/lo bf16 in registers.
__global__ __launch_bounds__(256, 6) void dec_fused(
    const _Float16* __restrict__ zsh, const int* __restrict__ rowptr,
    const int* __restrict__ col, const float* __restrict__ dinv,
    const float* __restrict__ b2,
    const u16* __restrict__ wd1h, const u16* __restrict__ wd1l,
    const u16* __restrict__ wd2h, const u16* __restrict__ wd2l,
    const float* __restrict__ bd1, const float* __restrict__ bd2,
    float* __restrict__ out, int M) {
    __shared__ _Float16 dsm[32 * 256];  // 16 KB; first 8KB = zt hi/lo planes

    const int tid = threadIdx.x;
    const int wid = tid >> 6, lane = tid & 63, quad = lane >> 4, lm = lane & 15;
    const int rt0 = blockIdx.x * 2;
    const int last_rt = (M >> 4) - 1;
    u16* const zt0 = (u16*)&dsm[0];         // [32*64] tiled
    u16* const zt1 = (u16*)&dsm[0] + 2048;

    // ---- agg prologue (agg64): 8 nodes per wave, 4-deep ----
    {
        const int slot = lane >> 4;
        const int c = (lane & 15) * 4;
        for (int r8 = 0; r8 < 8; r8++) {
            int node = blockIdx.x * 32 + wid * 8 + r8;
            if (node >= M) break;
            float4 a0 = make_float4(0.f, 0.f, 0.f, 0.f);
            float4 a1 = a0, a2 = a0, a3 = a0;
            if (slot == 0) acch(a0, ldh4(&zsh[(long)node * 64 + c]));
            int beg = rowptr[node];
            int end = rowptr[node + 1];
            for (int cb = beg; cb < end; cb += 64) {
                int cnt = min(64, end - cb);
                int cv = (lane < cnt) ? col[cb + lane] : 0;
                int full = cnt >> 2;
                int trips = (cnt + 3) >> 2;
                int t = 0;
                for (; t + 4 <= full; t += 4) {
                    int j = slot + 4 * t;
                    int s0 = __shfl(cv, j);
                    int s1 = __shfl(cv, j + 4);
                    int s2 = __shfl(cv, j + 8);
                    int s3 = __shfl(cv, j + 12);
                    f16x4 v0 = ldh4(&zsh[(long)s0 * 64 + c]);
                    f16x4 v1 = ldh4(&zsh[(long)s1 * 64 + c]);
                    f16x4 v2 = ldh4(&zsh[(long)s2 * 64 + c]);
                    f16x4 v3 = ldh4(&zsh[(long)s3 * 64 + c]);
                    acch(a0, v0); acch(a1, v1); acch(a2, v2); acch(a3, v3);
                }
                for (; t < trips; t++) {
                    int j = slot + 4 * t;
                    bool p = j < cnt;
                    int s = __shfl(cv, p ? j : 0);
                    if (p) acch(a0, ldh4(&zsh[(long)s * 64 + c]));
                }
            }
            acc4(a0, a1); acc4(a2, a3); acc4(a0, a2);
            a0.x += __shfl_xor(a0.x, 16); a0.x += __shfl_xor(a0.x, 32);
            a0.y += __shfl_xor(a0.y, 16); a0.y += __shfl_xor(a0.y, 32);
            a0.z += __shfl_xor(a0.z, 16); a0.z += __shfl_xor(a0.z, 32);
            a0.w += __shfl_xor(a0.w, 16); a0.w += __shfl_xor(a0.w, 32);
            if (slot == 0) {
                float di = dinv[node];
                float4 bi = ld4(&b2[c]);
                a0.x = a0.x * di + bi.x;
                a0.y = a0.y * di + bi.y;
                a0.z = a0.z * di + bi.z;
                a0.w = a0.w * di + bi.w;
                ushort4 h, l;
                split_bf16(a0.x, h.x, l.x);
                split_bf16(a0.y, h.y, l.y);
                split_bf16(a0.z, h.z, l.z);
                split_bf16(a0.w, h.w, l.w);
                int row = wid * 8 + r8;
                int o = ((row >> 4) * 8 + (c >> 3)) * 128 + ((row & 15) << 3) + (c & 7);
                *(ushort4*)&zt0[o] = h;
                *(ushort4*)&zt1[o] = l;
            }
        }
    }
    __syncthreads();

    // ---- stage A: d = relu(z @ Wd1 + bd1), K=64 (KB=8, KC=2) ----
    f32x4 acc[2][4];
#pragma unroll
    for (int i = 0; i < 2; i++)
#pragma unroll
        for (int j = 0; j < 4; j++) acc[i][j] = (f32x4){0.f, 0.f, 0.f, 0.f};

#pragma unroll
    for (int kc = 0; kc < 2; kc++) {
        const int kb = kc * 4 + quad;
        bf16x8 ah[2], al[2], bh[4], bl[4];
#pragma unroll
        for (int i = 0; i < 2; i++) {
            int lt = (rt0 + i <= last_rt) ? i : (last_rt - rt0);
            int o = (lt * 8 + kb) * 128 + lm * 8;
            ah[i] = *(const bf16x8*)&zt0[o];
            al[i] = *(const bf16x8*)&zt1[o];
        }
#pragma unroll
        for (int j = 0; j < 4; j++) {
            long o = ((long)(wid * 4 + j) * 8 + kb) * 128 + lm * 8;
            bh[j] = *(const bf16x8*)&wd1h[o];
            bl[j] = *(const bf16x8*)&wd1l[o];
        }
#pragma unroll
        for (int i = 0; i < 2; i++)
#pragma unroll
            for (int j = 0; j < 4; j++) { MFMA3(acc[i][j], ah[i], al[i], bh[j], bl[j]); }
    }
    __syncthreads();  // zt dead only after ALL waves read it (dsm aliases)

    // epilogue A -> LDS f16 tiled (overwrites zt region)
#pragma unroll
    for (int i = 0; i < 2; i++)
#pragma unroll
        for (int j = 0; j < 4; j++) {
            int coln = wid * 64 + j * 16 + lm;
            float bi = bd1[coln];
#pragma unroll
            for (int r = 0; r < 4; r++) {
                int row = i * 16 + quad * 4 + r;
                float v = fmaxf(acc[i][j][r] + bi, 0.f);
                int o = ((row >> 4) * 32 + (coln >> 3)) * 128 + ((row & 15) << 3) + (coln & 7);
                dsm[o] = (_Float16)v;
            }
        }
    __syncthreads();

    // ---- stage B: out = d @ Wd2 + bd2, K=256 (KB=32, KC=8) ----
    f32x4 acc2[2][2];
#pragma unroll
    for (int i = 0; i < 2; i++)
#pragma unroll
        for (int j = 0; j < 2; j++) acc2[i][j] = (f32x4){0.f, 0.f, 0.f, 0.f};
#pragma unroll
    for (int kc = 0; kc < 8; kc++) {
        const int kb = kc * 4 + quad;
        bf16x8 ah[2], al[2], bh[2], bl[2];
#pragma unroll
        for (int i = 0; i < 2; i++) {
            int o = (i * 32 + kb) * 128 + lm * 8;
            cvt_hilo(*(const f16x8*)&dsm[o], ah[i], al[i]);
        }
#pragma unroll
        for (int j = 0; j < 2; j++) {
            long o = ((long)(wid * 2 + j) * 32 + kb) * 128 + lm * 8;
            bh[j] = *(const bf16x8*)&wd2h[o];
            bl[j] = *(const bf16x8*)&wd2l[o];
        }
#pragma unroll
        for (int i = 0; i < 2; i++)
#pragma unroll
            for (int j = 0; j < 2; j++) { MFMA3(acc2[i][j], ah[i], al[i], bh[j], bl[j]); }
    }
#pragma unroll
    for (int i = 0; i < 2; i++)
#pragma unroll
        for (int j = 0; j < 2; j++) {
            int coln = wid * 32 + j * 16 + lm;
            float bi = bd2[coln];
#pragma unroll
            for (int r = 0; r < 4; r++) {
                int row = rt0 * 16 + i * 16 + quad * 4 + r;
                if (row < M) out[(long)row * 128 + coln] = acc2[i][j][r] + bi;
            }
        }
}

// ---------------- launch ----------------

extern "C" void kernel_launch(void* const* d_in, const int* in_sizes, int n_in,
                              void* d_out, int out_size, void* d_ws, size_t ws_size,
                              hipStream_t stream) {
    const float* x        = (const float*)d_in[0];
    const int* ei         = (const int*)d_in[1];   // int32 (harness integer convention)
    const float* W1       = (const float*)d_in[2];
    const float* b1       = (const float*)d_in[3];
    const float* W2       = (const float*)d_in[4];
    const float* b2       = (const float*)d_in[5];
    const float* Wd1      = (const float*)d_in[6];
    const float* bd1      = (const float*)d_in[7];
    const float* Wd2      = (const float*)d_in[8];
    const float* bd2      = (const float*)d_in[9];
    float* out            = (float*)d_out;

    const int N = in_sizes[0] / IN_CH;   // 50000 (multiple of 16)
    const int E = in_sizes[1] / 2;       // 800000

    char* p = (char*)d_ws;
    auto alloc = [&](size_t bytes) {
        char* r = p;
        p += (bytes + 255) & ~(size_t)255;
        return r;
    };
    int*      counts    = (int*)     alloc((size_t)(N + 1) * 4);
    int*      rowptr    = (int*)     alloc((size_t)(N + 1) * 4);
    int*      nxt       = (int*)     alloc((size_t)N * 4);
    int*      blocksums = (int*)     alloc(256 * 4);
    float*    dinv      = (float*)   alloc((size_t)N * 4);
    int*      col       = (int*)     alloc((size_t)E * 4);
    _Float16* xsh       = (_Float16*)alloc((size_t)N * IN_CH * 2);
    _Float16* zsh       = (_Float16*)alloc((size_t)N * LATENT * 2);
    u16*      w1t_hi    = (u16*)     alloc((size_t)IN_CH * HIDDEN * 2);
    u16*      w1t_lo    = (u16*)     alloc((size_t)IN_CH * HIDDEN * 2);
    u16*      w2t_hi    = (u16*)     alloc((size_t)HIDDEN * LATENT * 2);
    u16*      w2t_lo    = (u16*)     alloc((size_t)HIDDEN * LATENT * 2);
    u16*      wd1t_hi   = (u16*)     alloc((size_t)LATENT * HIDDEN * 2);
    u16*      wd1t_lo   = (u16*)     alloc((size_t)LATENT * HIDDEN * 2);
    u16*      wd2t_hi   = (u16*)     alloc((size_t)HIDDEN * IN_CH * 2);
    u16*      wd2t_lo   = (u16*)     alloc((size_t)HIDDEN * IN_CH * 2);

    const int nblk = (N + 255) / 256;            // 196
    const int total4 = N * (IN_CH / 4);
    const int chunks = (E + 255) / 256;          // edge chunks of 256
    const int nper = (N + 7) / 8;                // dst-range width per partition
    const int fblk = (N + 31) / 32;              // 1563

    hipMemsetAsync(counts, 0, (size_t)(N + 1) * 4, stream);
    hist_kernel<<<chunks * 8, 256, 0, stream>>>(ei, E, counts, nper);
    scan1_wsplit_kernel<<<nblk + 384, 256, 0, stream>>>(
        counts, rowptr, blocksums, dinv, N, nblk,
        W1, W2, Wd1, Wd2,
        w1t_hi, w1t_lo, w2t_hi, w2t_lo, wd1t_hi, wd1t_lo, wd2t_hi, wd2t_lo);
    scan3_prescale_kernel<<<(total4 + 255) / 256, 256, 0, stream>>>(
        rowptr, blocksums, nxt, x, dinv, xsh, N, total4, nblk);
    fill_kernel<<<chunks * 8, 256, 0, stream>>>(ei, E, nxt, col, nper);

    // enc_fused: [aggx prologue -> LDS] + zs = (relu(xa@W1+b1)@W2)*dinv
    enc_fused<<<fblk, 256, 0, stream>>>(xsh, rowptr, col, dinv,
                                        w1t_hi, w1t_lo, w2t_hi, w2t_lo,
                                        b1, zsh, N);
    // dec_fused: [agg64 prologue -> LDS] + out = relu(z@Wd1+bd1)@Wd2 + bd2
    dec_fused<<<fblk, 256, 0, stream>>>(zsh, rowptr, col, dinv, b2,
                                        wd1t_hi, wd1t_lo, wd2t_hi, wd2t_lo,
                                        bd1, bd2, out, N);
}

// Round 9
// 327.602 us; speedup vs baseline: 1.0241x; 1.0241x over previous
//
#include <hip/hip_runtime.h>

// GraphAE: 2x GCNConv encoder + 2-layer MLP decoder.
// N=50000, IN=128, HID=256, LAT=64, E=800000. fp32 in/out.
//
// R19 changes vs R18:
//  - SPILL FIX: R18's launch_bounds(256,6) + 8-deep gather forced VGPR
//    spilling to scratch (WRITE_SIZE 6.25->68MB, FETCH +32MB = smoking gun;
//    enc 106us DESPITE 46% occupancy). Revert gather to 4-deep (R17's
//    measured-48-VGPR shape) and use launch_bounds(256,8): VGPR cap 64 >=
//    ~50 natural -> no spill; 16KB LDS -> occupancy limiter is the wave-slot
//    ceiling (8 blocks/CU = 32 waves/CU, 1.6x R17's residency).
//  - KEEP R18's 16KB LDS: f16 o1/dsm plane + register cvt_hilo at stage-B
//    (absmax-verified bit-stable at 2.441e-4).
//  - R17: LDS time-multiplex. R16: agg-into-GEMM fusion (FETCH 189->81MB).
//    R14: f16 gather planes. R11: hist/fill dst-partition.
// (R15 grid-barrier fusion REVERTED: spin acquire = L2-inv storm on gfx950.)

#define IN_CH  128
#define HIDDEN 256
#define LATENT 64

typedef unsigned short u16;
typedef unsigned int u32;
typedef __bf16 bf16x8 __attribute__((ext_vector_type(8)));
typedef float f32x4 __attribute__((ext_vector_type(4)));
typedef _Float16 f16x4 __attribute__((ext_vector_type(4)));
typedef _Float16 f16x8 __attribute__((ext_vector_type(8)));
typedef u16 u16x8 __attribute__((ext_vector_type(8)));

static __device__ __forceinline__ float4 ld4(const float* p) {
    return *reinterpret_cast<const float4*>(p);
}
static __device__ __forceinline__ void acc4(float4& a, float4 v) {
    a.x += v.x; a.y += v.y; a.z += v.z; a.w += v.w;
}
static __device__ __forceinline__ f16x4 ldh4(const _Float16* p) {
    return *reinterpret_cast<const f16x4*>(p);
}
static __device__ __forceinline__ void acch(float4& a, f16x4 v) {
    a.x += (float)v[0]; a.y += (float)v[1]; a.z += (float)v[2]; a.w += (float)v[3];
}

// truncating hi/lo split: hi = top16(v); lo = top16(v - hi). v-hi exact.
static __device__ __forceinline__ void split_bf16(float v, u16& hi, u16& lo) {
    u32 b = __float_as_uint(v);
    hi = (u16)(b >> 16);
    float hf = __uint_as_float(b & 0xFFFF0000u);
    lo = (u16)(__float_as_uint(v - hf) >> 16);
}

// f16x8 -> hi/lo bf16x8 (register-side split for stage-B A-operand)
static __device__ __forceinline__ void cvt_hilo(f16x8 a, bf16x8& h, bf16x8& l) {
    u16x8 hh, ll;
#pragma unroll
    for (int k = 0; k < 8; k++) {
        float v = (float)a[k];
        u16 hi, lo;
        split_bf16(v, hi, lo);
        hh[k] = hi;
        ll[k] = lo;
    }
    h = __builtin_bit_cast(bf16x8, hh);
    l = __builtin_bit_cast(bf16x8, ll);
}

// tiled-layout offset (elements). K multiple of 8; row tiles of 16.
static __device__ __forceinline__ long tix(int row, int k, int K) {
    return ((long)(row >> 4) * (K >> 3) + (k >> 3)) * 128 + ((row & 15) << 3) + (k & 7);
}

#define MFMA3(ACC, AH, AL, BH, BL)                                             \
    ACC = __builtin_amdgcn_mfma_f32_16x16x32_bf16(AH, BH, ACC, 0, 0, 0);       \
    ACC = __builtin_amdgcn_mfma_f32_16x16x32_bf16(AH, BL, ACC, 0, 0, 0);       \
    ACC = __builtin_amdgcn_mfma_f32_16x16x32_bf16(AL, BH, ACC, 0, 0, 0);

// ---------------- graph structure kernels ----------------

// Partitioned histogram: block b handles edge chunk (b>>3), dst range (b&7).
__global__ void hist_kernel(const int* __restrict__ ei, int E,
                            int* __restrict__ counts, int nper) {
    int part = blockIdx.x & 7;
    int e = (blockIdx.x >> 3) * 256 + threadIdx.x;
    if (e >= E) return;
    int d = ei[E + e];
    if ((unsigned)(d - part * nper) < (unsigned)nper) atomicAdd(&counts[d], 1);
}

// scan1 (blocks < nblk) with dinv emit; wsplit rides along (blocks >= nblk).
__global__ void scan1_wsplit_kernel(
    const int* __restrict__ counts, int* __restrict__ rowptr,
    int* __restrict__ blocksums, float* __restrict__ dinv, int N, int nblk,
    const float* __restrict__ W1, const float* __restrict__ W2,
    const float* __restrict__ Wd1, const float* __restrict__ Wd2,
    u16* __restrict__ w1h, u16* __restrict__ w1l, u16* __restrict__ w2h, u16* __restrict__ w2l,
    u16* __restrict__ wd1h, u16* __restrict__ wd1l, u16* __restrict__ wd2h, u16* __restrict__ wd2l) {
    __shared__ int sh[256];
    int tid = threadIdx.x;
    if ((int)blockIdx.x < nblk) {
        int i = blockIdx.x * 256 + tid;
        int v = (i < N) ? counts[i] : 0;
        if (i < N) dinv[i] = rsqrtf((float)v + 1.0f);
        sh[tid] = v;
        __syncthreads();
        for (int off = 1; off < 256; off <<= 1) {
            int t = (tid >= off) ? sh[tid - off] : 0;
            __syncthreads();
            sh[tid] += t;
            __syncthreads();
        }
        if (i < N) rowptr[i] = sh[tid] - v;
        if (tid == 255) blocksums[blockIdx.x] = sh[255];
    } else {
        int idx = ((int)blockIdx.x - nblk) * 256 + tid;
        if (idx < 98304) {
            const float* W; u16 *H, *L; int K, Nn, base;
            if (idx < 32768)      { W = W1;  H = w1h;  L = w1l;  K = 128; Nn = 256; base = idx; }
            else if (idx < 49152) { W = W2;  H = w2h;  L = w2l;  K = 256; Nn = 64;  base = idx - 32768; }
            else if (idx < 65536) { W = Wd1; H = wd1h; L = wd1l; K = 64;  Nn = 256; base = idx - 49152; }
            else                  { W = Wd2; H = wd2h; L = wd2l; K = 256; Nn = 128; base = idx - 65536; }
            int k = base / Nn, n = base % Nn;
            u16 h, l;
            split_bf16(W[base], h, l);
            long o = tix(n, k, K);
            H[o] = h;
            L[o] = l;
        }
    }
}

// scan3 (+inlined scan2: blockoffs[b] = sum blocksums[0..b)) + prescale.
__global__ void scan3_prescale_kernel(
    int* __restrict__ rowptr, const int* __restrict__ blocksums, int* __restrict__ next,
    const float* __restrict__ x, const float* __restrict__ dinv, _Float16* __restrict__ xsh,
    int N, int total4, int nblk) {
    __shared__ int sh[256];
    const int b = blockIdx.x;
    const int tid = threadIdx.x;
    int boff = 0;
    if (b < nblk) {
        int s = 0;
        for (int j = tid; j < b; j += 256) s += blocksums[j];
        sh[tid] = s;
        __syncthreads();
        for (int off = 128; off > 0; off >>= 1) {
            if (tid < off) sh[tid] += sh[tid + off];
            __syncthreads();
        }
        boff = sh[0];
        if (b == nblk - 1 && tid == 0) rowptr[N] = boff + blocksums[b];
    }
    int i = b * 256 + tid;
    if (b < nblk && i < N) {
        int r = rowptr[i] + boff;
        rowptr[i] = r;
        next[i] = r;
    }
    if (i < total4) {
        float s = dinv[i >> 5];
        float4 v = ld4(&x[(long)i * 4]);
        f16x4 h;
        h[0] = (_Float16)(v.x * s);
        h[1] = (_Float16)(v.y * s);
        h[2] = (_Float16)(v.z * s);
        h[3] = (_Float16)(v.w * s);
        *reinterpret_cast<f16x4*>(&xsh[(long)i * 4]) = h;
    }
}

// Partitioned CSR fill: block b handles edge chunk (b>>3), dst range (b&7).
__global__ void fill_kernel(const int* __restrict__ ei, int E,
                            int* __restrict__ next, int* __restrict__ col, int nper) {
    int part = blockIdx.x & 7;
    int e = (blockIdx.x >> 3) * 256 + threadIdx.x;
    if (e >= E) return;
    int d = ei[E + e];
    if ((unsigned)(d - part * nper) < (unsigned)nper) {
        int s = ei[e];
        int pos = atomicAdd(&next[d], 1);
        col[pos] = s;
    }
}

// ---------------- fused agg+encoder (16KB LDS, no spill) ----------------
// Prologue: each wave aggregates 8 nodes (f16 gather 4-deep, fp32 acc, dinv
// scale) -> LDS bf16 hi/lo xa tile [32x128] (16KB). Stage A reads xa frags.
// o1 (stage A->B) is stored f16 [32x256] ALIASED over the same 16KB; stage B
// converts f16 -> hi/lo bf16 in registers. launch_bounds(256,8): VGPR<=64,
// wave-slot-limited occupancy (8 blocks/CU).
__global__ __launch_bounds__(256, 8) void enc_fused(
    const _Float16* __restrict__ xsh, const int* __restrict__ rowptr,
    const int* __restrict__ col, const float* __restrict__ dinv,
    const u16* __restrict__ w1h, const u16* __restrict__ w1l,
    const u16* __restrict__ w2h, const u16* __restrict__ w2l,
    const float* __restrict__ b1, _Float16* __restrict__ zsh, int M) {
    __shared__ u16 smem[2][32 * 128];  // 16 KB: xa hi/lo planes -> o1 f16

    const int tid = threadIdx.x;
    const int wid = tid >> 6, lane = tid & 63, quad = lane >> 4, lm = lane & 15;
    const int rt0 = blockIdx.x * 2;
    const int last_rt = (M >> 4) - 1;
    u16* const xa0 = &smem[0][0];
    u16* const xa1 = &smem[1][0];
    _Float16* const o1f = (_Float16*)&smem[0][0];  // [32*256] f16, aliased

    // ---- agg prologue (aggx): 8 nodes per wave, 4-deep pipeline ----
    {
        const int slot = lane >> 5;
        const int c = (lane & 31) * 4;
        for (int r8 = 0; r8 < 8; r8++) {
            int node = blockIdx.x * 32 + wid * 8 + r8;
            if (node >= M) break;
            float4 a0 = make_float4(0.f, 0.f, 0.f, 0.f);
            float4 a1 = a0, a2 = a0, a3 = a0;
            if (slot == 0) acch(a0, ldh4(&xsh[(long)node * 128 + c]));
            int beg = rowptr[node];
            int end = rowptr[node + 1];
            for (int cb = beg; cb < end; cb += 64) {
                int cnt = min(64, end - cb);
                int cv = (lane < cnt) ? col[cb + lane] : 0;
                int full = cnt >> 1;
                int trips = (cnt + 1) >> 1;
                int t = 0;
                for (; t + 4 <= full; t += 4) {
                    int j = slot + 2 * t;
                    int s0 = __shfl(cv, j);
                    int s1 = __shfl(cv, j + 2);
                    int s2 = __shfl(cv, j + 4);
                    int s3 = __shfl(cv, j + 6);
                    f16x4 v0 = ldh4(&xsh[(long)s0 * 128 + c]);
                    f16x4 v1 = ldh4(&xsh[(long)s1 * 128 + c]);
                    f16x4 v2 = ldh4(&xsh[(long)s2 * 128 + c]);
                    f16x4 v3 = ldh4(&xsh[(long)s3 * 128 + c]);
                    acch(a0, v0); acch(a1, v1); acch(a2, v2); acch(a3, v3);
                }
                for (; t < trips; t++) {
                    int j = slot + 2 * t;
                    bool p = j < cnt;
                    int s = __shfl(cv, p ? j : 0);
                    if (p) acch(a0, ldh4(&xsh[(long)s * 128 + c]));
                }
            }
            acc4(a0, a1); acc4(a2, a3); acc4(a0, a2);
            a0.x += __shfl_xor(a0.x, 32);
            a0.y += __shfl_xor(a0.y, 32);
            a0.z += __shfl_xor(a0.z, 32);
            a0.w += __shfl_xor(a0.w, 32);
            if (slot == 0) {
                float di = dinv[node];
                a0.x *= di; a0.y *= di; a0.z *= di; a0.w *= di;
                ushort4 h, l;
                split_bf16(a0.x, h.x, l.x);
                split_bf16(a0.y, h.y, l.y);
                split_bf16(a0.z, h.z, l.z);
                split_bf16(a0.w, h.w, l.w);
                int row = wid * 8 + r8;
                int o = ((row >> 4) * 16 + (c >> 3)) * 128 + ((row & 15) << 3) + (c & 7);
                *(ushort4*)&xa0[o] = h;
                *(ushort4*)&xa1[o] = l;
            }
        }
    }
    __syncthreads();

    // ---- stage A: out1 = relu(xa @ W1 + b1), K=128 (KB=16, KC=4) ----
    f32x4 acc[2][4];
#pragma unroll
    for (int i = 0; i < 2; i++)
#pragma unroll
        for (int j = 0; j < 4; j++) acc[i][j] = (f32x4){0.f, 0.f, 0.f, 0.f};

#pragma unroll
    for (int kc = 0; kc < 4; kc++) {
        const int kb = kc * 4 + quad;
        bf16x8 ah[2], al[2], bh[4], bl[4];
#pragma unroll
        for (int i = 0; i < 2; i++) {
            int lt = (rt0 + i <= last_rt) ? i : (last_rt - rt0);
            int o = (lt * 16 + kb) * 128 + lm * 8;
            ah[i] = *(const bf16x8*)&xa0[o];
            al[i] = *(const bf16x8*)&xa1[o];
        }
#pragma unroll
        for (int j = 0; j < 4; j++) {
            long o = ((long)(wid * 4 + j) * 16 + kb) * 128 + lm * 8;
            bh[j] = *(const bf16x8*)&w1h[o];
            bl[j] = *(const bf16x8*)&w1l[o];
        }
#pragma unroll
        for (int i = 0; i < 2; i++)
#pragma unroll
            for (int j = 0; j < 4; j++) { MFMA3(acc[i][j], ah[i], al[i], bh[j], bl[j]); }
    }
    __syncthreads();  // xa dead only after ALL waves read it (o1f aliases)

    // epilogue A -> LDS f16 tiled (overwrites xa region)
#pragma unroll
    for (int i = 0; i < 2; i++)
#pragma unroll
        for (int j = 0; j < 4; j++) {
            int coln = wid * 64 + j * 16 + lm;
            float bi = b1[coln];
#pragma unroll
            for (int r = 0; r < 4; r++) {
                int row = i * 16 + quad * 4 + r;
                float v = fmaxf(acc[i][j][r] + bi, 0.f);
                int o = ((row >> 4) * 32 + (coln >> 3)) * 128 + ((row & 15) << 3) + (coln & 7);
                o1f[o] = (_Float16)v;
            }
        }
    __syncthreads();

    // ---- stage B: zs = (out1 @ W2) * dinv, K=256 (KB=32, KC=8) ----
    f32x4 acc2[2];
    acc2[0] = (f32x4){0.f, 0.f, 0.f, 0.f};
    acc2[1] = (f32x4){0.f, 0.f, 0.f, 0.f};
#pragma unroll
    for (int kc = 0; kc < 8; kc++) {
        const int kb = kc * 4 + quad;
        bf16x8 ah[2], al[2], bh, bl;
#pragma unroll
        for (int i = 0; i < 2; i++) {
            int o = (i * 32 + kb) * 128 + lm * 8;
            cvt_hilo(*(const f16x8*)&o1f[o], ah[i], al[i]);
        }
        {
            long o = ((long)wid * 32 + kb) * 128 + lm * 8;
            bh = *(const bf16x8*)&w2h[o];
            bl = *(const bf16x8*)&w2l[o];
        }
#pragma unroll
        for (int i = 0; i < 2; i++) { MFMA3(acc2[i], ah[i], al[i], bh, bl); }
    }
#pragma unroll
    for (int i = 0; i < 2; i++) {
        int coln = wid * 16 + lm;
#pragma unroll
        for (int r = 0; r < 4; r++) {
            int row = rt0 * 16 + i * 16 + quad * 4 + r;
            if (row < M) zsh[(long)row * 64 + coln] = (_Float16)(acc2[i][r] * dinv[row]);
        }
    }
}

// ---------------- fused agg+decoder (16KB LDS, no spill) ----------------
// Prologue: each wave aggregates 8 nodes of z = dinv*(zs+sum zs)+b2 -> LDS
// bf16 hi/lo z tile [32x64] (8KB) aliased in dsm f16 [32x256] (16KB).
// Stage B converts f16 -> hi/lo bf16 in registers. launch_bounds(256,8).
__global__ __launch_bounds__(256, 8) void dec_fused(
    const _Float16* __restrict__ zsh, const int* __restrict__ rowptr,
    const int* __restrict__ col, const float* __restrict__ dinv,
    const float* __restrict__ b2,
    const u16* __restrict__ wd1h, const u16* __restrict__ wd1l,
    const u16* __restrict__ wd2h, const u16* __restrict__ wd2l,
    const float* __restrict__ bd1, const float* __restrict__ bd2,
    float* __restrict__ out, int M) {
    __shared__ _Float16 dsm[32 * 256];  // 16 KB; first 8KB = zt hi/lo planes

    const int tid = threadIdx.x;
    const int wid = tid >> 6, lane = tid & 63, quad = lane >> 4, lm = lane & 15;
    const int rt0 = blockIdx.x * 2;
    const int last_rt = (M >> 4) - 1;
    u16* const zt0 = (u16*)&dsm[0];         // [32*64] tiled
    u16* const zt1 = (u16*)&dsm[0] + 2048;

    // ---- agg prologue (agg64): 8 nodes per wave, 4-deep ----
    {
        const int slot = lane >> 4;
        const int c = (lane & 15) * 4;
        for (int r8 = 0; r8 < 8; r8++) {
            int node = blockIdx.x * 32 + wid * 8 + r8;
            if (node >= M) break;
            float4 a0 = make_float4(0.f, 0.f, 0.f, 0.f);
            float4 a1 = a0, a2 = a0, a3 = a0;
            if (slot == 0) acch(a0, ldh4(&zsh[(long)node * 64 + c]));
            int beg = rowptr[node];
            int end = rowptr[node + 1];
            for (int cb = beg; cb < end; cb += 64) {
                int cnt = min(64, end - cb);
                int cv = (lane < cnt) ? col[cb + lane] : 0;
                int full = cnt >> 2;
                int trips = (cnt + 3) >> 2;
                int t = 0;
                for (; t + 4 <= full; t += 4) {
                    int j = slot + 4 * t;
                    int s0 = __shfl(cv, j);
                    int s1 = __shfl(cv, j + 4);
                    int s2 = __shfl(cv, j + 8);
                    int s3 = __shfl(cv, j + 12);
                    f16x4 v0 = ldh4(&zsh[(long)s0 * 64 + c]);
                    f16x4 v1 = ldh4(&zsh[(long)s1 * 64 + c]);
                    f16x4 v2 = ldh4(&zsh[(long)s2 * 64 + c]);
                    f16x4 v3 = ldh4(&zsh[(long)s3 * 64 + c]);
                    acch(a0, v0); acch(a1, v1); acch(a2, v2); acch(a3, v3);
                }
                for (; t < trips; t++) {
                    int j = slot + 4 * t;
                    bool p = j < cnt;
                    int s = __shfl(cv, p ? j : 0);
                    if (p) acch(a0, ldh4(&zsh[(long)s * 64 + c]));
                }
            }
            acc4(a0, a1); acc4(a2, a3); acc4(a0, a2);
            a0.x += __shfl_xor(a0.x, 16); a0.x += __shfl_xor(a0.x, 32);
            a0.y += __shfl_xor(a0.y, 16); a0.y += __shfl_xor(a0.y, 32);
            a0.z += __shfl_xor(a0.z, 16); a0.z += __shfl_xor(a0.z, 32);
            a0.w += __shfl_xor(a0.w, 16); a0.w += __shfl_xor(a0.w, 32);
            if (slot == 0) {
                float di = dinv[node];
                float4 bi = ld4(&b2[c]);
                a0.x = a0.x * di + bi.x;
                a0.y = a0.y * di + bi.y;
                a0.z = a0.z * di + bi.z;
                a0.w = a0.w * di + bi.w;
                ushort4 h, l;
                split_bf16(a0.x, h.x, l.x);
                split_bf16(a0.y, h.y, l.y);
                split_bf16(a0.z, h.z, l.z);
                split_bf16(a0.w, h.w, l.w);
                int row = wid * 8 + r8;
                int o = ((row >> 4) * 8 + (c >> 3)) * 128 + ((row & 15) << 3) + (c & 7);
                *(ushort4*)&zt0[o] = h;
                *(ushort4*)&zt1[o] = l;
            }
        }
    }
    __syncthreads();

    // ---- stage A: d = relu(z @ Wd1 + bd1), K=64 (KB=8, KC=2) ----
    f32x4 acc[2][4];
#pragma unroll
    for (int i = 0; i < 2; i++)
#pragma unroll
        for (int j = 0; j < 4; j++) acc[i][j] = (f32x4){0.f, 0.f, 0.f, 0.f};

#pragma unroll
    for (int kc = 0; kc < 2; kc++) {
        const int kb = kc * 4 + quad;
        bf16x8 ah[2], al[2], bh[4], bl[4];
#pragma unroll
        for (int i = 0; i < 2; i++) {
            int lt = (rt0 + i <= last_rt) ? i : (last_rt - rt0);
            int o = (lt * 8 + kb) * 128 + lm * 8;
            ah[i] = *(const bf16x8*)&zt0[o];
            al[i] = *(const bf16x8*)&zt1[o];
        }
#pragma unroll
        for (int j = 0; j < 4; j++) {
            long o = ((long)(wid * 4 + j) * 8 + kb) * 128 + lm * 8;
            bh[j] = *(const bf16x8*)&wd1h[o];
            bl[j] = *(const bf16x8*)&wd1l[o];
        }
#pragma unroll
        for (int i = 0; i < 2; i++)
#pragma unroll
            for (int j = 0; j < 4; j++) { MFMA3(acc[i][j], ah[i], al[i], bh[j], bl[j]); }
    }
    __syncthreads();  // zt dead only after ALL waves read it (dsm aliases)

    // epilogue A -> LDS f16 tiled (overwrites zt region)
#pragma unroll
    for (int i = 0; i < 2; i++)
#pragma unroll
        for (int j = 0; j < 4; j++) {
            int coln = wid * 64 + j * 16 + lm;
            float bi = bd1[coln];
#pragma unroll
            for (int r = 0; r < 4; r++) {
                int row = i * 16 + quad * 4 + r;
                float v = fmaxf(acc[i][j][r] + bi, 0.f);
                int o = ((row >> 4) * 32 + (coln >> 3)) * 128 + ((row & 15) << 3) + (coln & 7);
                dsm[o] = (_Float16)v;
            }
        }
    __syncthreads();

    // ---- stage B: out = d @ Wd2 + bd2, K=256 (KB=32, KC=8) ----
    f32x4 acc2[2][2];
#pragma unroll
    for (int i = 0; i < 2; i++)
#pragma unroll
        for (int j = 0; j < 2; j++) acc2[i][j] = (f32x4){0.f, 0.f, 0.f, 0.f};
#pragma unroll
    for (int kc = 0; kc < 8; kc++) {
        const int kb = kc * 4 + quad;
        bf16x8 ah[2], al[2], bh[2], bl[2];
#pragma unroll
        for (int i = 0; i < 2; i++) {
            int o = (i * 32 + kb) * 128 + lm * 8;
            cvt_hilo(*(const f16x8*)&dsm[o], ah[i], al[i]);
        }
#pragma unroll
        for (int j = 0; j < 2; j++) {
            long o = ((long)(wid * 2 + j) * 32 + kb) * 128 + lm * 8;
            bh[j] = *(const bf16x8*)&wd2h[o];
            bl[j] = *(const bf16x8*)&wd2l[o];
        }
#pragma unroll
        for (int i = 0; i < 2; i++)
#pragma unroll
            for (int j = 0; j < 2; j++) { MFMA3(acc2[i][j], ah[i], al[i], bh[j], bl[j]); }
    }
#pragma unroll
    for (int i = 0; i < 2; i++)
#pragma unroll
        for (int j = 0; j < 2; j++) {
            int coln = wid * 32 + j * 16 + lm;
            float bi = bd2[coln];
#pragma unroll
            for (int r = 0; r < 4; r++) {
                int row = rt0 * 16 + i * 16 + quad * 4 + r;
                if (row < M) out[(long)row * 128 + coln] = acc2[i][j][r] + bi;
            }
        }
}

// ---------------- launch ----------------

extern "C" void kernel_launch(void* const* d_in, const int* in_sizes, int n_in,
                              void* d_out, int out_size, void* d_ws, size_t ws_size,
                              hipStream_t stream) {
    const float* x        = (const float*)d_in[0];
    const int* ei         = (const int*)d_in[1];   // int32 (harness integer convention)
    const float* W1       = (const float*)d_in[2];
    const float* b1       = (const float*)d_in[3];
    const float* W2       = (const float*)d_in[4];
    const float* b2       = (const float*)d_in[5];
    const float* Wd1      = (const float*)d_in[6];
    const float* bd1      = (const float*)d_in[7];
    const float* Wd2      = (const float*)d_in[8];
    const float* bd2      = (const float*)d_in[9];
    float* out            = (float*)d_out;

    const int N = in_sizes[0] / IN_CH;   // 50000 (multiple of 16)
    const int E = in_sizes[1] / 2;       // 800000

    char* p = (char*)d_ws;
    auto alloc = [&](size_t bytes) {
        char* r = p;
        p += (bytes + 255) & ~(size_t)255;
        return r;
    };
    int*      counts    = (int*)     alloc((size_t)(N + 1) * 4);
    int*      rowptr    = (int*)     alloc((size_t)(N + 1) * 4);
    int*      nxt       = (int*)     alloc((size_t)N * 4);
    int*      blocksums = (int*)     alloc(256 * 4);
    float*    dinv      = (float*)   alloc((size_t)N * 4);
    int*      col       = (int*)     alloc((size_t)E * 4);
    _Float16* xsh       = (_Float16*)alloc((size_t)N * IN_CH * 2);
    _Float16* zsh       = (_Float16*)alloc((size_t)N * LATENT * 2);
    u16*      w1t_hi    = (u16*)     alloc((size_t)IN_CH * HIDDEN * 2);
    u16*      w1t_lo    = (u16*)     alloc((size_t)IN_CH * HIDDEN * 2);
    u16*      w2t_hi    = (u16*)     alloc((size_t)HIDDEN * LATENT * 2);
    u16*      w2t_lo    = (u16*)     alloc((size_t)HIDDEN * LATENT * 2);
    u16*      wd1t_hi   = (u16*)     alloc((size_t)LATENT * HIDDEN * 2);
    u16*      wd1t_lo   = (u16*)     alloc((size_t)LATENT * HIDDEN * 2);
    u16*      wd2t_hi   = (u16*)     alloc((size_t)HIDDEN * IN_CH * 2);
    u16*      wd2t_lo   = (u16*)     alloc((size_t)HIDDEN * IN_CH * 2);

    const int nblk = (N + 255) / 256;            // 196
    const int total4 = N * (IN_CH / 4);
    const int chunks = (E + 255) / 256;          // edge chunks of 256
    const int nper = (N + 7) / 8;                // dst-range width per partition
    const int fblk = (N + 31) / 32;              // 1563

    hipMemsetAsync(counts, 0, (size_t)(N + 1) * 4, stream);
    hist_kernel<<<chunks * 8, 256, 0, stream>>>(ei, E, counts, nper);
    scan1_wsplit_kernel<<<nblk + 384, 256, 0, stream>>>(
        counts, rowptr, blocksums, dinv, N, nblk,
        W1, W2, Wd1, Wd2,
        w1t_hi, w1t_lo, w2t_hi, w2t_lo, wd1t_hi, wd1t_lo, wd2t_hi, wd2t_lo);
    scan3_prescale_kernel<<<(total4 + 255) / 256, 256, 0, stream>>>(
        rowptr, blocksums, nxt, x, dinv, xsh, N, total4, nblk);
    fill_kernel<<<chunks * 8, 256, 0, stream>>>(ei, E, nxt, col, nper);

    // enc_fused: [aggx prologue -> LDS] + zs = (relu(xa@W1+b1)@W2)*dinv
    enc_fused<<<fblk, 256, 0, stream>>>(xsh, rowptr, col, dinv,
                                        w1t_hi, w1t_lo, w2t_hi, w2t_lo,
                                        b1, zsh, N);
    // dec_fused: [agg64 prologue -> LDS] + out = relu(z@Wd1+bd1)@Wd2 + bd2
    dec_fused<<<fblk, 256, 0, stream>>>(zsh, rowptr, col, dinv, b2,
                                        wd1t_hi, wd1t_lo, wd2t_hi, wd2t_lo,
                                        bd1, bd2, out, N);
}

// Round 10
// 283.291 us; speedup vs baseline: 1.1843x; 1.1564x over previous
//
#include <hip/hip_runtime.h>

// GraphAE: 2x GCNConv encoder + 2-layer MLP decoder.
// N=50000, IN=128, HID=256, LAT=64, E=800000. fp32 in/out.
//
// R20 changes vs R19:
//  - FUSION ARC CLOSED (journal): agg-into-GEMM fusion cannot beat the split.
//    Gather phase wants occupancy (low VGPR); GEMM phase needs ~68+ VGPR.
//    One budget for both => spill (R18: 68MB, R19: 118MB scratch) or starved
//    gather (R16: 24%, R17: 31% occ). Best fused 305.6 vs split 285.0.
//  - REVERT to R14 split kernels: standalone aggx/agg64 (f16 gather, 4-deep,
//    wave=1 node, 32-40 VGPR, ~71% occ) + standalone enc/dec GEMMs reading
//    xa/z bf16 hi/lo tiled planes from HBM.
//  - KEEP R16 folding: wsplit rides scan1; scan2 inlined in scan3. 9 dispatches.
//  - KEEP R18 f16-o1: enc/dec stage-A->B intermediate as f16 plane (16KB LDS,
//    cvt_hilo at stage-B read; absmax-verified). No launch-bounds pins.
//  - R14: f16 gather planes. R11: hist/fill dst-partition (part = bid&7).
// (R15 grid-barrier fusion REVERTED: spin acquire = L2-inv storm on gfx950.)

#define IN_CH  128
#define HIDDEN 256
#define LATENT 64

typedef unsigned short u16;
typedef unsigned int u32;
typedef __bf16 bf16x8 __attribute__((ext_vector_type(8)));
typedef float f32x4 __attribute__((ext_vector_type(4)));
typedef _Float16 f16x4 __attribute__((ext_vector_type(4)));
typedef _Float16 f16x8 __attribute__((ext_vector_type(8)));
typedef u16 u16x8 __attribute__((ext_vector_type(8)));

static __device__ __forceinline__ float4 ld4(const float* p) {
    return *reinterpret_cast<const float4*>(p);
}
static __device__ __forceinline__ void acc4(float4& a, float4 v) {
    a.x += v.x; a.y += v.y; a.z += v.z; a.w += v.w;
}
static __device__ __forceinline__ f16x4 ldh4(const _Float16* p) {
    return *reinterpret_cast<const f16x4*>(p);
}
static __device__ __forceinline__ void acch(float4& a, f16x4 v) {
    a.x += (float)v[0]; a.y += (float)v[1]; a.z += (float)v[2]; a.w += (float)v[3];
}

// truncating hi/lo split: hi = top16(v); lo = top16(v - hi). v-hi exact.
static __device__ __forceinline__ void split_bf16(float v, u16& hi, u16& lo) {
    u32 b = __float_as_uint(v);
    hi = (u16)(b >> 16);
    float hf = __uint_as_float(b & 0xFFFF0000u);
    lo = (u16)(__float_as_uint(v - hf) >> 16);
}

// f16x8 -> hi/lo bf16x8 (register-side split for stage-B A-operand)
static __device__ __forceinline__ void cvt_hilo(f16x8 a, bf16x8& h, bf16x8& l) {
    u16x8 hh, ll;
#pragma unroll
    for (int k = 0; k < 8; k++) {
        float v = (float)a[k];
        u16 hi, lo;
        split_bf16(v, hi, lo);
        hh[k] = hi;
        ll[k] = lo;
    }
    h = __builtin_bit_cast(bf16x8, hh);
    l = __builtin_bit_cast(bf16x8, ll);
}

// tiled-layout offset (elements). K multiple of 8; row tiles of 16.
static __device__ __forceinline__ long tix(int row, int k, int K) {
    return ((long)(row >> 4) * (K >> 3) + (k >> 3)) * 128 + ((row & 15) << 3) + (k & 7);
}

#define MFMA3(ACC, AH, AL, BH, BL)                                             \
    ACC = __builtin_amdgcn_mfma_f32_16x16x32_bf16(AH, BH, ACC, 0, 0, 0);       \
    ACC = __builtin_amdgcn_mfma_f32_16x16x32_bf16(AH, BL, ACC, 0, 0, 0);       \
    ACC = __builtin_amdgcn_mfma_f32_16x16x32_bf16(AL, BH, ACC, 0, 0, 0);

// ---------------- graph structure kernels ----------------

// Partitioned histogram: block b handles edge chunk (b>>3), dst range (b&7).
__global__ void hist_kernel(const int* __restrict__ ei, int E,
                            int* __restrict__ counts, int nper) {
    int part = blockIdx.x & 7;
    int e = (blockIdx.x >> 3) * 256 + threadIdx.x;
    if (e >= E) return;
    int d = ei[E + e];
    if ((unsigned)(d - part * nper) < (unsigned)nper) atomicAdd(&counts[d], 1);
}

// scan1 (blocks < nblk) with dinv emit; wsplit rides along (blocks >= nblk).
__global__ void scan1_wsplit_kernel(
    const int* __restrict__ counts, int* __restrict__ rowptr,
    int* __restrict__ blocksums, float* __restrict__ dinv, int N, int nblk,
    const float* __restrict__ W1, const float* __restrict__ W2,
    const float* __restrict__ Wd1, const float* __restrict__ Wd2,
    u16* __restrict__ w1h, u16* __restrict__ w1l, u16* __restrict__ w2h, u16* __restrict__ w2l,
    u16* __restrict__ wd1h, u16* __restrict__ wd1l, u16* __restrict__ wd2h, u16* __restrict__ wd2l) {
    __shared__ int sh[256];
    int tid = threadIdx.x;
    if ((int)blockIdx.x < nblk) {
        int i = blockIdx.x * 256 + tid;
        int v = (i < N) ? counts[i] : 0;
        if (i < N) dinv[i] = rsqrtf((float)v + 1.0f);
        sh[tid] = v;
        __syncthreads();
        for (int off = 1; off < 256; off <<= 1) {
            int t = (tid >= off) ? sh[tid - off] : 0;
            __syncthreads();
            sh[tid] += t;
            __syncthreads();
        }
        if (i < N) rowptr[i] = sh[tid] - v;
        if (tid == 255) blocksums[blockIdx.x] = sh[255];
    } else {
        int idx = ((int)blockIdx.x - nblk) * 256 + tid;
        if (idx < 98304) {
            const float* W; u16 *H, *L; int K, Nn, base;
            if (idx < 32768)      { W = W1;  H = w1h;  L = w1l;  K = 128; Nn = 256; base = idx; }
            else if (idx < 49152) { W = W2;  H = w2h;  L = w2l;  K = 256; Nn = 64;  base = idx - 32768; }
            else if (idx < 65536) { W = Wd1; H = wd1h; L = wd1l; K = 64;  Nn = 256; base = idx - 49152; }
            else                  { W = Wd2; H = wd2h; L = wd2l; K = 256; Nn = 128; base = idx - 65536; }
            int k = base / Nn, n = base % Nn;
            u16 h, l;
            split_bf16(W[base], h, l);
            long o = tix(n, k, K);
            H[o] = h;
            L[o] = l;
        }
    }
}

// scan3 (+inlined scan2: blockoffs[b] = sum blocksums[0..b)) + prescale.
__global__ void scan3_prescale_kernel(
    int* __restrict__ rowptr, const int* __restrict__ blocksums, int* __restrict__ next,
    const float* __restrict__ x, const float* __restrict__ dinv, _Float16* __restrict__ xsh,
    int N, int total4, int nblk) {
    __shared__ int sh[256];
    const int b = blockIdx.x;
    const int tid = threadIdx.x;
    int boff = 0;
    if (b < nblk) {
        int s = 0;
        for (int j = tid; j < b; j += 256) s += blocksums[j];
        sh[tid] = s;
        __syncthreads();
        for (int off = 128; off > 0; off >>= 1) {
            if (tid < off) sh[tid] += sh[tid + off];
            __syncthreads();
        }
        boff = sh[0];
        if (b == nblk - 1 && tid == 0) rowptr[N] = boff + blocksums[b];
    }
    int i = b * 256 + tid;
    if (b < nblk && i < N) {
        int r = rowptr[i] + boff;
        rowptr[i] = r;
        next[i] = r;
    }
    if (i < total4) {
        float s = dinv[i >> 5];
        float4 v = ld4(&x[(long)i * 4]);
        f16x4 h;
        h[0] = (_Float16)(v.x * s);
        h[1] = (_Float16)(v.y * s);
        h[2] = (_Float16)(v.z * s);
        h[3] = (_Float16)(v.w * s);
        *reinterpret_cast<f16x4*>(&xsh[(long)i * 4]) = h;
    }
}

// Partitioned CSR fill: block b handles edge chunk (b>>3), dst range (b&7).
__global__ void fill_kernel(const int* __restrict__ ei, int E,
                            int* __restrict__ next, int* __restrict__ col, int nper) {
    int part = blockIdx.x & 7;
    int e = (blockIdx.x >> 3) * 256 + threadIdx.x;
    if (e >= E) return;
    int d = ei[E + e];
    if ((unsigned)(d - part * nper) < (unsigned)nper) {
        int s = ei[e];
        int pos = atomicAdd(&next[d], 1);
        col[pos] = s;
    }
}

// ---------------- aggregation kernels (standalone, R14 shapes) ----------------

// AGGX: xa[i] = dinv[i]*(xs[i] + sum_in xs[s]); f16 gather (256B rows),
// fp32 accumulate; writes TILED hi/lo planes. Wave = 1 node, 2 edge-slots x
// 32 lanes x 8B. 4-deep load pipeline.
__global__ __launch_bounds__(256) void aggx_kernel(
    const _Float16* __restrict__ xsh, const int* __restrict__ rowptr,
    const int* __restrict__ col, const float* __restrict__ dinv,
    u16* __restrict__ xahi, u16* __restrict__ xalo, int N) {
    int wid = threadIdx.x >> 6;
    int lane = threadIdx.x & 63;
    int node = blockIdx.x * 4 + wid;
    if (node >= N) return;
    int slot = lane >> 5;
    int c = (lane & 31) * 4;  // channel offset (4 f16 = 8B per lane)

    float4 a0 = make_float4(0.f, 0.f, 0.f, 0.f);
    float4 a1 = a0, a2 = a0, a3 = a0;
    if (slot == 0) acch(a0, ldh4(&xsh[(long)node * 128 + c]));

    int beg = rowptr[node];
    int end = rowptr[node + 1];
    for (int cb = beg; cb < end; cb += 64) {
        int cnt = min(64, end - cb);
        int cv = (lane < cnt) ? col[cb + lane] : 0;
        int full = cnt >> 1;
        int trips = (cnt + 1) >> 1;
        int t = 0;
        for (; t + 4 <= full; t += 4) {
            int j = slot + 2 * t;
            int s0 = __shfl(cv, j);
            int s1 = __shfl(cv, j + 2);
            int s2 = __shfl(cv, j + 4);
            int s3 = __shfl(cv, j + 6);
            f16x4 v0 = ldh4(&xsh[(long)s0 * 128 + c]);
            f16x4 v1 = ldh4(&xsh[(long)s1 * 128 + c]);
            f16x4 v2 = ldh4(&xsh[(long)s2 * 128 + c]);
            f16x4 v3 = ldh4(&xsh[(long)s3 * 128 + c]);
            acch(a0, v0); acch(a1, v1); acch(a2, v2); acch(a3, v3);
        }
        for (; t < trips; t++) {
            int j = slot + 2 * t;
            bool p = j < cnt;
            int s = __shfl(cv, p ? j : 0);
            if (p) acch(a0, ldh4(&xsh[(long)s * 128 + c]));
        }
    }
    acc4(a0, a1); acc4(a2, a3); acc4(a0, a2);
    a0.x += __shfl_xor(a0.x, 32);
    a0.y += __shfl_xor(a0.y, 32);
    a0.z += __shfl_xor(a0.z, 32);
    a0.w += __shfl_xor(a0.w, 32);
    if (slot == 0) {
        float di = dinv[node];
        a0.x *= di; a0.y *= di; a0.z *= di; a0.w *= di;
        ushort4 h, l;
        split_bf16(a0.x, h.x, l.x);
        split_bf16(a0.y, h.y, l.y);
        split_bf16(a0.z, h.z, l.z);
        split_bf16(a0.w, h.w, l.w);
        long o = tix(node, c, 128);
        *(ushort4*)&xahi[o] = h;
        *(ushort4*)&xalo[o] = l;
    }
}

// AGG2: z[i] = dinv[i]*(zs[i] + sum_in zs[s]) + b2; f16 gather (128B rows),
// fp32 accumulate; writes TILED hi/lo planes. Wave = 1 node, 4 edge-slots x
// 16 lanes x 8B. 4-deep pipeline.
__global__ __launch_bounds__(256) void agg64_kernel(
    const _Float16* __restrict__ zsh, const int* __restrict__ rowptr,
    const int* __restrict__ col, const float* __restrict__ dinv,
    const float* __restrict__ bias,
    u16* __restrict__ zhi, u16* __restrict__ zlo, int N) {
    int wid = threadIdx.x >> 6;
    int lane = threadIdx.x & 63;
    int node = blockIdx.x * 4 + wid;
    if (node >= N) return;
    int slot = lane >> 4;
    int c = (lane & 15) * 4;  // channel offset (4 f16 = 8B per lane)

    float4 a0 = make_float4(0.f, 0.f, 0.f, 0.f);
    float4 a1 = a0, a2 = a0, a3 = a0;
    if (slot == 0) acch(a0, ldh4(&zsh[(long)node * 64 + c]));

    int beg = rowptr[node];
    int end = rowptr[node + 1];
    for (int cb = beg; cb < end; cb += 64) {
        int cnt = min(64, end - cb);
        int cv = (lane < cnt) ? col[cb + lane] : 0;
        int full = cnt >> 2;
        int trips = (cnt + 3) >> 2;
        int t = 0;
        for (; t + 4 <= full; t += 4) {
            int j = slot + 4 * t;
            int s0 = __shfl(cv, j);
            int s1 = __shfl(cv, j + 4);
            int s2 = __shfl(cv, j + 8);
            int s3 = __shfl(cv, j + 12);
            f16x4 v0 = ldh4(&zsh[(long)s0 * 64 + c]);
            f16x4 v1 = ldh4(&zsh[(long)s1 * 64 + c]);
            f16x4 v2 = ldh4(&zsh[(long)s2 * 64 + c]);
            f16x4 v3 = ldh4(&zsh[(long)s3 * 64 + c]);
            acch(a0, v0); acch(a1, v1); acch(a2, v2); acch(a3, v3);
        }
        for (; t < trips; t++) {
            int j = slot + 4 * t;
            bool p = j < cnt;
            int s = __shfl(cv, p ? j : 0);
            if (p) acch(a0, ldh4(&zsh[(long)s * 64 + c]));
        }
    }
    acc4(a0, a1); acc4(a2, a3); acc4(a0, a2);
    a0.x += __shfl_xor(a0.x, 16); a0.x += __shfl_xor(a0.x, 32);
    a0.y += __shfl_xor(a0.y, 16); a0.y += __shfl_xor(a0.y, 32);
    a0.z += __shfl_xor(a0.z, 16); a0.z += __shfl_xor(a0.z, 32);
    a0.w += __shfl_xor(a0.w, 16); a0.w += __shfl_xor(a0.w, 32);
    if (slot == 0) {
        float di = dinv[node];
        float4 bi = ld4(&bias[c]);
        a0.x = a0.x * di + bi.x;
        a0.y = a0.y * di + bi.y;
        a0.z = a0.z * di + bi.z;
        a0.w = a0.w * di + bi.w;
        ushort4 h, l;
        split_bf16(a0.x, h.x, l.x);
        split_bf16(a0.y, h.y, l.y);
        split_bf16(a0.z, h.z, l.z);
        split_bf16(a0.w, h.w, l.w);
        long o = tix(node, c, 64);
        *(ushort4*)&zhi[o] = h;
        *(ushort4*)&zlo[o] = l;
    }
}

// ---------------- fused encoder GEMM: zs = (relu(xa@W1+b1) @ W2) * dinv ----
// Reads xa bf16 hi/lo TILED planes from HBM. o1 intermediate stored as f16
// LDS plane (16KB); stage B converts f16 -> hi/lo bf16 in registers.
__global__ __launch_bounds__(256) void enc_fused(
    const u16* __restrict__ xa_hi, const u16* __restrict__ xa_lo,
    const u16* __restrict__ w1h, const u16* __restrict__ w1l,
    const u16* __restrict__ w2h, const u16* __restrict__ w2l,
    const float* __restrict__ b1, const float* __restrict__ dinv,
    _Float16* __restrict__ zsh, int M) {
    __shared__ _Float16 o1f[32 * 256];  // 16 KB

    const int tid = threadIdx.x;
    const int wid = tid >> 6, lane = tid & 63, quad = lane >> 4, lm = lane & 15;
    const int rt0 = blockIdx.x * 2;
    const int last_rt = (M >> 4) - 1;

    // ---- stage A: out1 = relu(xa @ W1 + b1), K=128 (KB=16, KC=4) ----
    f32x4 acc[2][4];
#pragma unroll
    for (int i = 0; i < 2; i++)
#pragma unroll
        for (int j = 0; j < 4; j++) acc[i][j] = (f32x4){0.f, 0.f, 0.f, 0.f};

#pragma unroll
    for (int kc = 0; kc < 4; kc++) {
        const int kb = kc * 4 + quad;
        bf16x8 ah[2], al[2], bh[4], bl[4];
#pragma unroll
        for (int i = 0; i < 2; i++) {
            int rt = rt0 + i; rt = rt <= last_rt ? rt : last_rt;
            long o = ((long)rt * 16 + kb) * 128 + lm * 8;
            ah[i] = *(const bf16x8*)&xa_hi[o];
            al[i] = *(const bf16x8*)&xa_lo[o];
        }
#pragma unroll
        for (int j = 0; j < 4; j++) {
            long o = ((long)(wid * 4 + j) * 16 + kb) * 128 + lm * 8;
            bh[j] = *(const bf16x8*)&w1h[o];
            bl[j] = *(const bf16x8*)&w1l[o];
        }
#pragma unroll
        for (int i = 0; i < 2; i++)
#pragma unroll
            for (int j = 0; j < 4; j++) { MFMA3(acc[i][j], ah[i], al[i], bh[j], bl[j]); }
    }

    // epilogue A -> LDS f16 tiled
#pragma unroll
    for (int i = 0; i < 2; i++)
#pragma unroll
        for (int j = 0; j < 4; j++) {
            int coln = wid * 64 + j * 16 + lm;
            float bi = b1[coln];
#pragma unroll
            for (int r = 0; r < 4; r++) {
                int row = i * 16 + quad * 4 + r;
                float v = fmaxf(acc[i][j][r] + bi, 0.f);
                int o = ((row >> 4) * 32 + (coln >> 3)) * 128 + ((row & 15) << 3) + (coln & 7);
                o1f[o] = (_Float16)v;
            }
        }
    __syncthreads();

    // ---- stage B: zs = (out1 @ W2) * dinv, K=256 (KB=32, KC=8) ----
    f32x4 acc2[2];
    acc2[0] = (f32x4){0.f, 0.f, 0.f, 0.f};
    acc2[1] = (f32x4){0.f, 0.f, 0.f, 0.f};
#pragma unroll
    for (int kc = 0; kc < 8; kc++) {
        const int kb = kc * 4 + quad;
        bf16x8 ah[2], al[2], bh, bl;
#pragma unroll
        for (int i = 0; i < 2; i++) {
            int o = (i * 32 + kb) * 128 + lm * 8;
            cvt_hilo(*(const f16x8*)&o1f[o], ah[i], al[i]);
        }
        {
            long o = ((long)wid * 32 + kb) * 128 + lm * 8;
            bh = *(const bf16x8*)&w2h[o];
            bl = *(const bf16x8*)&w2l[o];
        }
#pragma unroll
        for (int i = 0; i < 2; i++) { MFMA3(acc2[i], ah[i], al[i], bh, bl); }
    }
#pragma unroll
    for (int i = 0; i < 2; i++) {
        int coln = wid * 16 + lm;
#pragma unroll
        for (int r = 0; r < 4; r++) {
            int row = rt0 * 16 + i * 16 + quad * 4 + r;
            if (row < M) zsh[(long)row * 64 + coln] = (_Float16)(acc2[i][r] * dinv[row]);
        }
    }
}

// ---------------- fused decoder GEMM: out = relu(z@Wd1+bd1)@Wd2 + bd2 ----
// Reads z bf16 hi/lo TILED planes from HBM. dsm intermediate stored f16 (16KB).
__global__ __launch_bounds__(256) void dec_fused(
    const u16* __restrict__ z_hi, const u16* __restrict__ z_lo,
    const u16* __restrict__ wd1h, const u16* __restrict__ wd1l,
    const u16* __restrict__ wd2h, const u16* __restrict__ wd2l,
    const float* __restrict__ bd1, const float* __restrict__ bd2,
    float* __restrict__ out, int M) {
    __shared__ _Float16 dsm[32 * 256];  // 16 KB

    const int tid = threadIdx.x;
    const int wid = tid >> 6, lane = tid & 63, quad = lane >> 4, lm = lane & 15;
    const int rt0 = blockIdx.x * 2;
    const int last_rt = (M >> 4) - 1;

    // ---- stage A: d = relu(z @ Wd1 + bd1), K=64 (KB=8, KC=2) ----
    f32x4 acc[2][4];
#pragma unroll
    for (int i = 0; i < 2; i++)
#pragma unroll
        for (int j = 0; j < 4; j++) acc[i][j] = (f32x4){0.f, 0.f, 0.f, 0.f};

#pragma unroll
    for (int kc = 0; kc < 2; kc++) {
        const int kb = kc * 4 + quad;
        bf16x8 ah[2], al[2], bh[4], bl[4];
#pragma unroll
        for (int i = 0; i < 2; i++) {
            int rt = rt0 + i; rt = rt <= last_rt ? rt : last_rt;
            long o = ((long)rt * 8 + kb) * 128 + lm * 8;
            ah[i] = *(const bf16x8*)&z_hi[o];
            al[i] = *(const bf16x8*)&z_lo[o];
        }
#pragma unroll
        for (int j = 0; j < 4; j++) {
            long o = ((long)(wid * 4 + j) * 8 + kb) * 128 + lm * 8;
            bh[j] = *(const bf16x8*)&wd1h[o];
            bl[j] = *(const bf16x8*)&wd1l[o];
        }
#pragma unroll
        for (int i = 0; i < 2; i++)
#pragma unroll
            for (int j = 0; j < 4; j++) { MFMA3(acc[i][j], ah[i], al[i], bh[j], bl[j]); }
    }

    // epilogue A -> LDS f16 tiled
#pragma unroll
    for (int i = 0; i < 2; i++)
#pragma unroll
        for (int j = 0; j < 4; j++) {
            int coln = wid * 64 + j * 16 + lm;
            float bi = bd1[coln];
#pragma unroll
            for (int r = 0; r < 4; r++) {
                int row = i * 16 + quad * 4 + r;
                float v = fmaxf(acc[i][j][r] + bi, 0.f);
                int o = ((row >> 4) * 32 + (coln >> 3)) * 128 + ((row & 15) << 3) + (coln & 7);
                dsm[o] = (_Float16)v;
            }
        }
    __syncthreads();

    // ---- stage B: out = d @ Wd2 + bd2, K=256 (KB=32, KC=8) ----
    f32x4 acc2[2][2];
#pragma unroll
    for (int i = 0; i < 2; i++)
#pragma unroll
        for (int j = 0; j < 2; j++) acc2[i][j] = (f32x4){0.f, 0.f, 0.f, 0.f};
#pragma unroll
    for (int kc = 0; kc < 8; kc++) {
        const int kb = kc * 4 + quad;
        bf16x8 ah[2], al[2], bh[2], bl[2];
#pragma unroll
        for (int i = 0; i < 2; i++) {
            int o = (i * 32 + kb) * 128 + lm * 8;
            cvt_hilo(*(const f16x8*)&dsm[o], ah[i], al[i]);
        }
#pragma unroll
        for (int j = 0; j < 2; j++) {
            long o = ((long)(wid * 2 + j) * 32 + kb) * 128 + lm * 8;
            bh[j] = *(const bf16x8*)&wd2h[o];
            bl[j] = *(const bf16x8*)&wd2l[o];
        }
#pragma unroll
        for (int i = 0; i < 2; i++)
#pragma unroll
            for (int j = 0; j < 2; j++) { MFMA3(acc2[i][j], ah[i], al[i], bh[j], bl[j]); }
    }
#pragma unroll
    for (int i = 0; i < 2; i++)
#pragma unroll
        for (int j = 0; j < 2; j++) {
            int coln = wid * 32 + j * 16 + lm;
            float bi = bd2[coln];
#pragma unroll
            for (int r = 0; r < 4; r++) {
                int row = rt0 * 16 + i * 16 + quad * 4 + r;
                if (row < M) out[(long)row * 128 + coln] = acc2[i][j][r] + bi;
            }
        }
}

// ---------------- launch ----------------

extern "C" void kernel_launch(void* const* d_in, const int* in_sizes, int n_in,
                              void* d_out, int out_size, void* d_ws, size_t ws_size,
                              hipStream_t stream) {
    const float* x        = (const float*)d_in[0];
    const int* ei         = (const int*)d_in[1];   // int32 (harness integer convention)
    const float* W1       = (const float*)d_in[2];
    const float* b1       = (const float*)d_in[3];
    const float* W2       = (const float*)d_in[4];
    const float* b2       = (const float*)d_in[5];
    const float* Wd1      = (const float*)d_in[6];
    const float* bd1      = (const float*)d_in[7];
    const float* Wd2      = (const float*)d_in[8];
    const float* bd2      = (const float*)d_in[9];
    float* out            = (float*)d_out;

    const int N = in_sizes[0] / IN_CH;   // 50000 (multiple of 16)
    const int E = in_sizes[1] / 2;       // 800000

    char* p = (char*)d_ws;
    auto alloc = [&](size_t bytes) {
        char* r = p;
        p += (bytes + 255) & ~(size_t)255;
        return r;
    };
    int*      counts    = (int*)     alloc((size_t)(N + 1) * 4);
    int*      rowptr    = (int*)     alloc((size_t)(N + 1) * 4);
    int*      nxt       = (int*)     alloc((size_t)N * 4);
    int*      blocksums = (int*)     alloc(256 * 4);
    float*    dinv      = (float*)   alloc((size_t)N * 4);
    int*      col       = (int*)     alloc((size_t)E * 4);
    _Float16* xsh       = (_Float16*)alloc((size_t)N * IN_CH * 2);
    u16*      xa_hi     = (u16*)     alloc((size_t)N * IN_CH * 2);
    u16*      xa_lo     = (u16*)     alloc((size_t)N * IN_CH * 2);
    _Float16* zsh       = (_Float16*)alloc((size_t)N * LATENT * 2);
    u16*      z_hi      = (u16*)     alloc((size_t)N * LATENT * 2);
    u16*      z_lo      = (u16*)     alloc((size_t)N * LATENT * 2);
    u16*      w1t_hi    = (u16*)     alloc((size_t)IN_CH * HIDDEN * 2);
    u16*      w1t_lo    = (u16*)     alloc((size_t)IN_CH * HIDDEN * 2);
    u16*      w2t_hi    = (u16*)     alloc((size_t)HIDDEN * LATENT * 2);
    u16*      w2t_lo    = (u16*)     alloc((size_t)HIDDEN * LATENT * 2);
    u16*      wd1t_hi   = (u16*)     alloc((size_t)LATENT * HIDDEN * 2);
    u16*      wd1t_lo   = (u16*)     alloc((size_t)LATENT * HIDDEN * 2);
    u16*      wd2t_hi   = (u16*)     alloc((size_t)HIDDEN * IN_CH * 2);
    u16*      wd2t_lo   = (u16*)     alloc((size_t)HIDDEN * IN_CH * 2);

    const int nblk = (N + 255) / 256;            // 196
    const int total4 = N * (IN_CH / 4);
    const int chunks = (E + 255) / 256;          // edge chunks of 256
    const int nper = (N + 7) / 8;                // dst-range width per partition
    const int fblk = (N + 31) / 32;              // 1563

    hipMemsetAsync(counts, 0, (size_t)(N + 1) * 4, stream);
    hist_kernel<<<chunks * 8, 256, 0, stream>>>(ei, E, counts, nper);
    scan1_wsplit_kernel<<<nblk + 384, 256, 0, stream>>>(
        counts, rowptr, blocksums, dinv, N, nblk,
        W1, W2, Wd1, Wd2,
        w1t_hi, w1t_lo, w2t_hi, w2t_lo, wd1t_hi, wd1t_lo, wd2t_hi, wd2t_lo);
    scan3_prescale_kernel<<<(total4 + 255) / 256, 256, 0, stream>>>(
        rowptr, blocksums, nxt, x, dinv, xsh, N, total4, nblk);
    fill_kernel<<<chunks * 8, 256, 0, stream>>>(ei, E, nxt, col, nper);

    // AGGX: xa = D^-1/2 A^ D^-1/2 X (f16 gather, tiled bf16 hi/lo out)
    aggx_kernel<<<(N + 3) / 4, 256, 0, stream>>>(xsh, rowptr, col, dinv, xa_hi, xa_lo, N);
    // enc: zs = (relu(xa@W1+b1)@W2)*dinv  (f16 out)
    enc_fused<<<fblk, 256, 0, stream>>>(xa_hi, xa_lo, w1t_hi, w1t_lo,
                                        w2t_hi, w2t_lo, b1, dinv, zsh, N);
    // AGG2: z = dinv*(sum zs) + b2 -> tiled bf16 hi/lo (f16 gather)
    agg64_kernel<<<(N + 3) / 4, 256, 0, stream>>>(zsh, rowptr, col, dinv, b2, z_hi, z_lo, N);
    // dec: out = relu(z@Wd1+bd1)@Wd2 + bd2
    dec_fused<<<fblk, 256, 0, stream>>>(z_hi, z_lo, wd1t_hi, wd1t_lo,
                                        wd2t_hi, wd2t_lo, bd1, bd2, out, N);
}

// Round 11
// 260.413 us; speedup vs baseline: 1.2883x; 1.0879x over previous
//
#include <hip/hip_runtime.h>

// GraphAE: 2x GCNConv encoder + 2-layer MLP decoder.
// N=50000, IN=128, HID=256, LAT=64, E=800000. fp32 in/out.
//
// R21 changes vs R20:
//  - NATIVE f16 MFMA GEMMs: weights/xa/z stored as single f16 tiled planes;
//    enc/dec use mfma_f32_16x16x32_f16 (1 MFMA per product vs hi/lo bf16's 3),
//    fp32 accumulate. cvt_hilo + all split_bf16 epilogues deleted; stage-B
//    LDS f16 reads feed MFMA directly. Evidence: absmax pinned at exactly
//    2^-12 across FOUR prior f16 (2^-11-class) insertions (xs/zs/o1/dsm,
//    R14/R18) -> pipeline error floor is elsewhere; hi/lo tax (3x MFMA,
//    VALU splits, 2x operand bytes) buys nothing observable. Predicted
//    absmax 3-6e-4 (pass); if it fails, revert GEMMs only.
//  - R20: split agg/GEMM structure (fusion arc closed: one VGPR budget can't
//    serve latency-bound gather AND register-hungry MFMA).
//  - R16 folding kept: wsplit rides scan1; scan2 inlined in scan3. 9 dispatches.
//  - R14: f16 gather planes. R11: hist/fill dst-partition (part = bid&7).
// (R15 grid-barrier fusion REVERTED: spin acquire = L2-inv storm on gfx950.)

#define IN_CH  128
#define HIDDEN 256
#define LATENT 64

typedef unsigned short u16;
typedef unsigned int u32;
typedef float f32x4 __attribute__((ext_vector_type(4)));
typedef _Float16 f16x4 __attribute__((ext_vector_type(4)));
typedef _Float16 f16x8 __attribute__((ext_vector_type(8)));

static __device__ __forceinline__ float4 ld4(const float* p) {
    return *reinterpret_cast<const float4*>(p);
}
static __device__ __forceinline__ void acc4(float4& a, float4 v) {
    a.x += v.x; a.y += v.y; a.z += v.z; a.w += v.w;
}
static __device__ __forceinline__ f16x4 ldh4(const _Float16* p) {
    return *reinterpret_cast<const f16x4*>(p);
}
static __device__ __forceinline__ void acch(float4& a, f16x4 v) {
    a.x += (float)v[0]; a.y += (float)v[1]; a.z += (float)v[2]; a.w += (float)v[3];
}

// tiled-layout offset (elements). K multiple of 8; row tiles of 16.
static __device__ __forceinline__ long tix(int row, int k, int K) {
    return ((long)(row >> 4) * (K >> 3) + (k >> 3)) * 128 + ((row & 15) << 3) + (k & 7);
}

#define MFMA16(ACC, A, B)                                                      \
    ACC = __builtin_amdgcn_mfma_f32_16x16x32_f16(A, B, ACC, 0, 0, 0);

// ---------------- graph structure kernels ----------------

// Partitioned histogram: block b handles edge chunk (b>>3), dst range (b&7).
__global__ void hist_kernel(const int* __restrict__ ei, int E,
                            int* __restrict__ counts, int nper) {
    int part = blockIdx.x & 7;
    int e = (blockIdx.x >> 3) * 256 + threadIdx.x;
    if (e >= E) return;
    int d = ei[E + e];
    if ((unsigned)(d - part * nper) < (unsigned)nper) atomicAdd(&counts[d], 1);
}

// scan1 (blocks < nblk) with dinv emit; wsplit rides along (blocks >= nblk).
__global__ void scan1_wsplit_kernel(
    const int* __restrict__ counts, int* __restrict__ rowptr,
    int* __restrict__ blocksums, float* __restrict__ dinv, int N, int nblk,
    const float* __restrict__ W1, const float* __restrict__ W2,
    const float* __restrict__ Wd1, const float* __restrict__ Wd2,
    _Float16* __restrict__ w1f, _Float16* __restrict__ w2f,
    _Float16* __restrict__ wd1f, _Float16* __restrict__ wd2f) {
    __shared__ int sh[256];
    int tid = threadIdx.x;
    if ((int)blockIdx.x < nblk) {
        int i = blockIdx.x * 256 + tid;
        int v = (i < N) ? counts[i] : 0;
        if (i < N) dinv[i] = rsqrtf((float)v + 1.0f);
        sh[tid] = v;
        __syncthreads();
        for (int off = 1; off < 256; off <<= 1) {
            int t = (tid >= off) ? sh[tid - off] : 0;
            __syncthreads();
            sh[tid] += t;
            __syncthreads();
        }
        if (i < N) rowptr[i] = sh[tid] - v;
        if (tid == 255) blocksums[blockIdx.x] = sh[255];
    } else {
        int idx = ((int)blockIdx.x - nblk) * 256 + tid;
        if (idx < 98304) {
            const float* W; _Float16* H; int K, Nn, base;
            if (idx < 32768)      { W = W1;  H = w1f;  K = 128; Nn = 256; base = idx; }
            else if (idx < 49152) { W = W2;  H = w2f;  K = 256; Nn = 64;  base = idx - 32768; }
            else if (idx < 65536) { W = Wd1; H = wd1f; K = 64;  Nn = 256; base = idx - 49152; }
            else                  { W = Wd2; H = wd2f; K = 256; Nn = 128; base = idx - 65536; }
            int k = base / Nn, n = base % Nn;
            H[tix(n, k, K)] = (_Float16)W[base];
        }
    }
}

// scan3 (+inlined scan2: blockoffs[b] = sum blocksums[0..b)) + prescale.
__global__ void scan3_prescale_kernel(
    int* __restrict__ rowptr, const int* __restrict__ blocksums, int* __restrict__ next,
    const float* __restrict__ x, const float* __restrict__ dinv, _Float16* __restrict__ xsh,
    int N, int total4, int nblk) {
    __shared__ int sh[256];
    const int b = blockIdx.x;
    const int tid = threadIdx.x;
    int boff = 0;
    if (b < nblk) {
        int s = 0;
        for (int j = tid; j < b; j += 256) s += blocksums[j];
        sh[tid] = s;
        __syncthreads();
        for (int off = 128; off > 0; off >>= 1) {
            if (tid < off) sh[tid] += sh[tid + off];
            __syncthreads();
        }
        boff = sh[0];
        if (b == nblk - 1 && tid == 0) rowptr[N] = boff + blocksums[b];
    }
    int i = b * 256 + tid;
    if (b < nblk && i < N) {
        int r = rowptr[i] + boff;
        rowptr[i] = r;
        next[i] = r;
    }
    if (i < total4) {
        float s = dinv[i >> 5];
        float4 v = ld4(&x[(long)i * 4]);
        f16x4 h;
        h[0] = (_Float16)(v.x * s);
        h[1] = (_Float16)(v.y * s);
        h[2] = (_Float16)(v.z * s);
        h[3] = (_Float16)(v.w * s);
        *reinterpret_cast<f16x4*>(&xsh[(long)i * 4]) = h;
    }
}

// Partitioned CSR fill: block b handles edge chunk (b>>3), dst range (b&7).
__global__ void fill_kernel(const int* __restrict__ ei, int E,
                            int* __restrict__ next, int* __restrict__ col, int nper) {
    int part = blockIdx.x & 7;
    int e = (blockIdx.x >> 3) * 256 + threadIdx.x;
    if (e >= E) return;
    int d = ei[E + e];
    if ((unsigned)(d - part * nper) < (unsigned)nper) {
        int s = ei[e];
        int pos = atomicAdd(&next[d], 1);
        col[pos] = s;
    }
}

// ---------------- aggregation kernels (standalone, R14 shapes) ----------------

// AGGX: xa[i] = dinv[i]*(xs[i] + sum_in xs[s]); f16 gather (256B rows),
// fp32 accumulate; writes TILED f16 plane. Wave = 1 node, 2 edge-slots x
// 32 lanes x 8B. 4-deep load pipeline.
__global__ __launch_bounds__(256) void aggx_kernel(
    const _Float16* __restrict__ xsh, const int* __restrict__ rowptr,
    const int* __restrict__ col, const float* __restrict__ dinv,
    _Float16* __restrict__ xaf, int N) {
    int wid = threadIdx.x >> 6;
    int lane = threadIdx.x & 63;
    int node = blockIdx.x * 4 + wid;
    if (node >= N) return;
    int slot = lane >> 5;
    int c = (lane & 31) * 4;  // channel offset (4 f16 = 8B per lane)

    float4 a0 = make_float4(0.f, 0.f, 0.f, 0.f);
    float4 a1 = a0, a2 = a0, a3 = a0;
    if (slot == 0) acch(a0, ldh4(&xsh[(long)node * 128 + c]));

    int beg = rowptr[node];
    int end = rowptr[node + 1];
    for (int cb = beg; cb < end; cb += 64) {
        int cnt = min(64, end - cb);
        int cv = (lane < cnt) ? col[cb + lane] : 0;
        int full = cnt >> 1;
        int trips = (cnt + 1) >> 1;
        int t = 0;
        for (; t + 4 <= full; t += 4) {
            int j = slot + 2 * t;
            int s0 = __shfl(cv, j);
            int s1 = __shfl(cv, j + 2);
            int s2 = __shfl(cv, j + 4);
            int s3 = __shfl(cv, j + 6);
            f16x4 v0 = ldh4(&xsh[(long)s0 * 128 + c]);
            f16x4 v1 = ldh4(&xsh[(long)s1 * 128 + c]);
            f16x4 v2 = ldh4(&xsh[(long)s2 * 128 + c]);
            f16x4 v3 = ldh4(&xsh[(long)s3 * 128 + c]);
            acch(a0, v0); acch(a1, v1); acch(a2, v2); acch(a3, v3);
        }
        for (; t < trips; t++) {
            int j = slot + 2 * t;
            bool p = j < cnt;
            int s = __shfl(cv, p ? j : 0);
            if (p) acch(a0, ldh4(&xsh[(long)s * 128 + c]));
        }
    }
    acc4(a0, a1); acc4(a2, a3); acc4(a0, a2);
    a0.x += __shfl_xor(a0.x, 32);
    a0.y += __shfl_xor(a0.y, 32);
    a0.z += __shfl_xor(a0.z, 32);
    a0.w += __shfl_xor(a0.w, 32);
    if (slot == 0) {
        float di = dinv[node];
        f16x4 h;
        h[0] = (_Float16)(a0.x * di);
        h[1] = (_Float16)(a0.y * di);
        h[2] = (_Float16)(a0.z * di);
        h[3] = (_Float16)(a0.w * di);
        *(f16x4*)&xaf[tix(node, c, 128)] = h;
    }
}

// AGG2: z[i] = dinv[i]*(zs[i] + sum_in zs[s]) + b2; f16 gather (128B rows),
// fp32 accumulate; writes TILED f16 plane. Wave = 1 node, 4 edge-slots x
// 16 lanes x 8B. 4-deep pipeline.
__global__ __launch_bounds__(256) void agg64_kernel(
    const _Float16* __restrict__ zsh, const int* __restrict__ rowptr,
    const int* __restrict__ col, const float* __restrict__ dinv,
    const float* __restrict__ bias,
    _Float16* __restrict__ zf, int N) {
    int wid = threadIdx.x >> 6;
    int lane = threadIdx.x & 63;
    int node = blockIdx.x * 4 + wid;
    if (node >= N) return;
    int slot = lane >> 4;
    int c = (lane & 15) * 4;  // channel offset (4 f16 = 8B per lane)

    float4 a0 = make_float4(0.f, 0.f, 0.f, 0.f);
    float4 a1 = a0, a2 = a0, a3 = a0;
    if (slot == 0) acch(a0, ldh4(&zsh[(long)node * 64 + c]));

    int beg = rowptr[node];
    int end = rowptr[node + 1];
    for (int cb = beg; cb < end; cb += 64) {
        int cnt = min(64, end - cb);
        int cv = (lane < cnt) ? col[cb + lane] : 0;
        int full = cnt >> 2;
        int trips = (cnt + 3) >> 2;
        int t = 0;
        for (; t + 4 <= full; t += 4) {
            int j = slot + 4 * t;
            int s0 = __shfl(cv, j);
            int s1 = __shfl(cv, j + 4);
            int s2 = __shfl(cv, j + 8);
            int s3 = __shfl(cv, j + 12);
            f16x4 v0 = ldh4(&zsh[(long)s0 * 64 + c]);
            f16x4 v1 = ldh4(&zsh[(long)s1 * 64 + c]);
            f16x4 v2 = ldh4(&zsh[(long)s2 * 64 + c]);
            f16x4 v3 = ldh4(&zsh[(long)s3 * 64 + c]);
            acch(a0, v0); acch(a1, v1); acch(a2, v2); acch(a3, v3);
        }
        for (; t < trips; t++) {
            int j = slot + 4 * t;
            bool p = j < cnt;
            int s = __shfl(cv, p ? j : 0);
            if (p) acch(a0, ldh4(&zsh[(long)s * 64 + c]));
        }
    }
    acc4(a0, a1); acc4(a2, a3); acc4(a0, a2);
    a0.x += __shfl_xor(a0.x, 16); a0.x += __shfl_xor(a0.x, 32);
    a0.y += __shfl_xor(a0.y, 16); a0.y += __shfl_xor(a0.y, 32);
    a0.z += __shfl_xor(a0.z, 16); a0.z += __shfl_xor(a0.z, 32);
    a0.w += __shfl_xor(a0.w, 16); a0.w += __shfl_xor(a0.w, 32);
    if (slot == 0) {
        float di = dinv[node];
        float4 bi = ld4(&bias[c]);
        f16x4 h;
        h[0] = (_Float16)(a0.x * di + bi.x);
        h[1] = (_Float16)(a0.y * di + bi.y);
        h[2] = (_Float16)(a0.z * di + bi.z);
        h[3] = (_Float16)(a0.w * di + bi.w);
        *(f16x4*)&zf[tix(node, c, 64)] = h;
    }
}

// ---------------- encoder GEMM: zs = (relu(xa@W1+b1) @ W2) * dinv ----------
// All operands f16 (tiled planes); native f16 MFMA, fp32 accumulate.
// o1 intermediate f16 in LDS (16KB), read directly as stage-B A-operand.
__global__ __launch_bounds__(256) void enc_fused(
    const _Float16* __restrict__ xaf,
    const _Float16* __restrict__ w1f, const _Float16* __restrict__ w2f,
    const float* __restrict__ b1, const float* __restrict__ dinv,
    _Float16* __restrict__ zsh, int M) {
    __shared__ _Float16 o1f[32 * 256];  // 16 KB

    const int tid = threadIdx.x;
    const int wid = tid >> 6, lane = tid & 63, quad = lane >> 4, lm = lane & 15;
    const int rt0 = blockIdx.x * 2;
    const int last_rt = (M >> 4) - 1;

    // ---- stage A: out1 = relu(xa @ W1 + b1), K=128 (KB=16, KC=4) ----
    f32x4 acc[2][4];
#pragma unroll
    for (int i = 0; i < 2; i++)
#pragma unroll
        for (int j = 0; j < 4; j++) acc[i][j] = (f32x4){0.f, 0.f, 0.f, 0.f};

#pragma unroll
    for (int kc = 0; kc < 4; kc++) {
        const int kb = kc * 4 + quad;
        f16x8 a[2], b[4];
#pragma unroll
        for (int i = 0; i < 2; i++) {
            int rt = rt0 + i; rt = rt <= last_rt ? rt : last_rt;
            long o = ((long)rt * 16 + kb) * 128 + lm * 8;
            a[i] = *(const f16x8*)&xaf[o];
        }
#pragma unroll
        for (int j = 0; j < 4; j++) {
            long o = ((long)(wid * 4 + j) * 16 + kb) * 128 + lm * 8;
            b[j] = *(const f16x8*)&w1f[o];
        }
#pragma unroll
        for (int i = 0; i < 2; i++)
#pragma unroll
            for (int j = 0; j < 4; j++) { MFMA16(acc[i][j], a[i], b[j]); }
    }

    // epilogue A -> LDS f16 tiled
#pragma unroll
    for (int i = 0; i < 2; i++)
#pragma unroll
        for (int j = 0; j < 4; j++) {
            int coln = wid * 64 + j * 16 + lm;
            float bi = b1[coln];
#pragma unroll
            for (int r = 0; r < 4; r++) {
                int row = i * 16 + quad * 4 + r;
                float v = fmaxf(acc[i][j][r] + bi, 0.f);
                int o = ((row >> 4) * 32 + (coln >> 3)) * 128 + ((row & 15) << 3) + (coln & 7);
                o1f[o] = (_Float16)v;
            }
        }
    __syncthreads();

    // ---- stage B: zs = (out1 @ W2) * dinv, K=256 (KB=32, KC=8) ----
    f32x4 acc2[2];
    acc2[0] = (f32x4){0.f, 0.f, 0.f, 0.f};
    acc2[1] = (f32x4){0.f, 0.f, 0.f, 0.f};
#pragma unroll
    for (int kc = 0; kc < 8; kc++) {
        const int kb = kc * 4 + quad;
        f16x8 a[2], b;
#pragma unroll
        for (int i = 0; i < 2; i++) {
            int o = (i * 32 + kb) * 128 + lm * 8;
            a[i] = *(const f16x8*)&o1f[o];
        }
        {
            long o = ((long)wid * 32 + kb) * 128 + lm * 8;
            b = *(const f16x8*)&w2f[o];
        }
#pragma unroll
        for (int i = 0; i < 2; i++) { MFMA16(acc2[i], a[i], b); }
    }
#pragma unroll
    for (int i = 0; i < 2; i++) {
        int coln = wid * 16 + lm;
#pragma unroll
        for (int r = 0; r < 4; r++) {
            int row = rt0 * 16 + i * 16 + quad * 4 + r;
            if (row < M) zsh[(long)row * 64 + coln] = (_Float16)(acc2[i][r] * dinv[row]);
        }
    }
}

// ---------------- decoder GEMM: out = relu(z@Wd1+bd1)@Wd2 + bd2 ----------
// All operands f16 (tiled planes); native f16 MFMA, fp32 accumulate.
__global__ __launch_bounds__(256) void dec_fused(
    const _Float16* __restrict__ zf,
    const _Float16* __restrict__ wd1f, const _Float16* __restrict__ wd2f,
    const float* __restrict__ bd1, const float* __restrict__ bd2,
    float* __restrict__ out, int M) {
    __shared__ _Float16 dsm[32 * 256];  // 16 KB

    const int tid = threadIdx.x;
    const int wid = tid >> 6, lane = tid & 63, quad = lane >> 4, lm = lane & 15;
    const int rt0 = blockIdx.x * 2;
    const int last_rt = (M >> 4) - 1;

    // ---- stage A: d = relu(z @ Wd1 + bd1), K=64 (KB=8, KC=2) ----
    f32x4 acc[2][4];
#pragma unroll
    for (int i = 0; i < 2; i++)
#pragma unroll
        for (int j = 0; j < 4; j++) acc[i][j] = (f32x4){0.f, 0.f, 0.f, 0.f};

#pragma unroll
    for (int kc = 0; kc < 2; kc++) {
        const int kb = kc * 4 + quad;
        f16x8 a[2], b[4];
#pragma unroll
        for (int i = 0; i < 2; i++) {
            int rt = rt0 + i; rt = rt <= last_rt ? rt : last_rt;
            long o = ((long)rt * 8 + kb) * 128 + lm * 8;
            a[i] = *(const f16x8*)&zf[o];
        }
#pragma unroll
        for (int j = 0; j < 4; j++) {
            long o = ((long)(wid * 4 + j) * 8 + kb) * 128 + lm * 8;
            b[j] = *(const f16x8*)&wd1f[o];
        }
#pragma unroll
        for (int i = 0; i < 2; i++)
#pragma unroll
            for (int j = 0; j < 4; j++) { MFMA16(acc[i][j], a[i], b[j]); }
    }

    // epilogue A -> LDS f16 tiled
#pragma unroll
    for (int i = 0; i < 2; i++)
#pragma unroll
        for (int j = 0; j < 4; j++) {
            int coln = wid * 64 + j * 16 + lm;
            float bi = bd1[coln];
#pragma unroll
            for (int r = 0; r < 4; r++) {
                int row = i * 16 + quad * 4 + r;
                float v = fmaxf(acc[i][j][r] + bi, 0.f);
                int o = ((row >> 4) * 32 + (coln >> 3)) * 128 + ((row & 15) << 3) + (coln & 7);
                dsm[o] = (_Float16)v;
            }
        }
    __syncthreads();

    // ---- stage B: out = d @ Wd2 + bd2, K=256 (KB=32, KC=8) ----
    f32x4 acc2[2][2];
#pragma unroll
    for (int i = 0; i < 2; i++)
#pragma unroll
        for (int j = 0; j < 2; j++) acc2[i][j] = (f32x4){0.f, 0.f, 0.f, 0.f};
#pragma unroll
    for (int kc = 0; kc < 8; kc++) {
        const int kb = kc * 4 + quad;
        f16x8 a[2], b[2];
#pragma unroll
        for (int i = 0; i < 2; i++) {
            int o = (i * 32 + kb) * 128 + lm * 8;
            a[i] = *(const f16x8*)&dsm[o];
        }
#pragma unroll
        for (int j = 0; j < 2; j++) {
            long o = ((long)(wid * 2 + j) * 32 + kb) * 128 + lm * 8;
            b[j] = *(const f16x8*)&wd2f[o];
        }
#pragma unroll
        for (int i = 0; i < 2; i++)
#pragma unroll
            for (int j = 0; j < 2; j++) { MFMA16(acc2[i][j], a[i], b[j]); }
    }
#pragma unroll
    for (int i = 0; i < 2; i++)
#pragma unroll
        for (int j = 0; j < 2; j++) {
            int coln = wid * 32 + j * 16 + lm;
            float bi = bd2[coln];
#pragma unroll
            for (int r = 0; r < 4; r++) {
                int row = rt0 * 16 + i * 16 + quad * 4 + r;
                if (row < M) out[(long)row * 128 + coln] = acc2[i][j][r] + bi;
            }
        }
}

// ---------------- launch ----------------

extern "C" void kernel_launch(void* const* d_in, const int* in_sizes, int n_in,
                              void* d_out, int out_size, void* d_ws, size_t ws_size,
                              hipStream_t stream) {
    const float* x        = (const float*)d_in[0];
    const int* ei         = (const int*)d_in[1];   // int32 (harness integer convention)
    const float* W1       = (const float*)d_in[2];
    const float* b1       = (const float*)d_in[3];
    const float* W2       = (const float*)d_in[4];
    const float* b2       = (const float*)d_in[5];
    const float* Wd1      = (const float*)d_in[6];
    const float* bd1      = (const float*)d_in[7];
    const float* Wd2      = (const float*)d_in[8];
    const float* bd2      = (const float*)d_in[9];
    float* out            = (float*)d_out;

    const int N = in_sizes[0] / IN_CH;   // 50000 (multiple of 16)
    const int E = in_sizes[1] / 2;       // 800000

    char* p = (char*)d_ws;
    auto alloc = [&](size_t bytes) {
        char* r = p;
        p += (bytes + 255) & ~(size_t)255;
        return r;
    };
    int*      counts    = (int*)     alloc((size_t)(N + 1) * 4);
    int*      rowptr    = (int*)     alloc((size_t)(N + 1) * 4);
    int*      nxt       = (int*)     alloc((size_t)N * 4);
    int*      blocksums = (int*)     alloc(256 * 4);
    float*    dinv      = (float*)   alloc((size_t)N * 4);
    int*      col       = (int*)     alloc((size_t)E * 4);
    _Float16* xsh       = (_Float16*)alloc((size_t)N * IN_CH * 2);
    _Float16* xaf       = (_Float16*)alloc((size_t)N * IN_CH * 2);
    _Float16* zsh       = (_Float16*)alloc((size_t)N * LATENT * 2);
    _Float16* zf        = (_Float16*)alloc((size_t)N * LATENT * 2);
    _Float16* w1f       = (_Float16*)alloc((size_t)IN_CH * HIDDEN * 2);
    _Float16* w2f       = (_Float16*)alloc((size_t)HIDDEN * LATENT * 2);
    _Float16* wd1f      = (_Float16*)alloc((size_t)LATENT * HIDDEN * 2);
    _Float16* wd2f      = (_Float16*)alloc((size_t)HIDDEN * IN_CH * 2);

    const int nblk = (N + 255) / 256;            // 196
    const int total4 = N * (IN_CH / 4);
    const int chunks = (E + 255) / 256;          // edge chunks of 256
    const int nper = (N + 7) / 8;                // dst-range width per partition
    const int fblk = (N + 31) / 32;              // 1563

    hipMemsetAsync(counts, 0, (size_t)(N + 1) * 4, stream);
    hist_kernel<<<chunks * 8, 256, 0, stream>>>(ei, E, counts, nper);
    scan1_wsplit_kernel<<<nblk + 384, 256, 0, stream>>>(
        counts, rowptr, blocksums, dinv, N, nblk,
        W1, W2, Wd1, Wd2, w1f, w2f, wd1f, wd2f);
    scan3_prescale_kernel<<<(total4 + 255) / 256, 256, 0, stream>>>(
        rowptr, blocksums, nxt, x, dinv, xsh, N, total4, nblk);
    fill_kernel<<<chunks * 8, 256, 0, stream>>>(ei, E, nxt, col, nper);

    // AGGX: xa = D^-1/2 A^ D^-1/2 X (f16 gather, tiled f16 out)
    aggx_kernel<<<(N + 3) / 4, 256, 0, stream>>>(xsh, rowptr, col, dinv, xaf, N);
    // enc: zs = (relu(xa@W1+b1)@W2)*dinv  (f16 MFMA, f16 out)
    enc_fused<<<fblk, 256, 0, stream>>>(xaf, w1f, w2f, b1, dinv, zsh, N);
    // AGG2: z = dinv*(sum zs) + b2 -> tiled f16 (f16 gather)
    agg64_kernel<<<(N + 3) / 4, 256, 0, stream>>>(zsh, rowptr, col, dinv, b2, zf, N);
    // dec: out = relu(z@Wd1+bd1)@Wd2 + bd2  (f16 MFMA)
    dec_fused<<<fblk, 256, 0, stream>>>(zf, wd1f, wd2f, bd1, bd2, out, N);
}